// Round 4
// baseline (230.319 us; speedup 1.0000x reference)
//
#include <hip/hip_runtime.h>
#include <hip/hip_bf16.h>
#include <math.h>

#define Bsz 4
#define Nseq 2048
#define Dm 256
#define Hh 8
#define Hd 32
#define EPS_ 1e-5f
#define SCALE_ 0.17677669529663687f  // 1/sqrt(32)

typedef __attribute__((ext_vector_type(8))) short short8;
typedef __attribute__((ext_vector_type(4))) short short4v;
typedef __attribute__((ext_vector_type(4))) float f32x4;

// async global->LDS, 16B per lane. LDS dest = wave-uniform base + lane*16.
__device__ __forceinline__ void gload16(const void* g, void* l) {
    __builtin_amdgcn_global_load_lds(
        (const __attribute__((address_space(1))) void*)g,
        (__attribute__((address_space(3))) void*)l, 16, 0, 0);
}

__device__ __forceinline__ short8 read8x2(const __hip_bfloat16* p) {
    short4v lo = *(const short4v*)p;
    short4v hi = *(const short4v*)(p + 4);
    return __builtin_shufflevector(lo, hi, 0, 1, 2, 3, 4, 5, 6, 7);
}

__device__ __forceinline__ short bf16s(float f) {
    __hip_bfloat16 h = __float2bfloat16(f);
    return *(short*)&h;
}

// ---------------- Weight transpose+convert: fp32 [K][N] -> bf16 [N][K] -----
__global__ __launch_bounds__(256) void wconv_kernel(
    const float* __restrict__ s0, const float* __restrict__ s1,
    const float* __restrict__ s2, const float* __restrict__ s3,
    __hip_bfloat16* __restrict__ d0, __hip_bfloat16* __restrict__ d1,
    __hip_bfloat16* __restrict__ d2, __hip_bfloat16* __restrict__ d3) {
    __shared__ float t[32][33];
    int bid = blockIdx.x;
    const float* src; __hip_bfloat16* dst; int K, N, tb;
    if (bid < 192)      { src = s0; dst = d0; K = 256; N = 768; tb = bid; }
    else if (bid < 256) { src = s1; dst = d1; K = 256; N = 256; tb = bid - 192; }
    else if (bid < 384) { src = s2; dst = d2; K = 256; N = 512; tb = bid - 256; }
    else                { src = s3; dst = d3; K = 512; N = 256; tb = bid - 384; }
    int tn = N >> 5;
    int k0 = (tb / tn) * 32, n0 = (tb % tn) * 32;
    int c = threadIdx.x & 31, r0 = threadIdx.x >> 5;
    #pragma unroll
    for (int i = 0; i < 4; i++) {
        int r = r0 + i * 8;
        t[r][c] = src[(size_t)(k0 + r) * N + n0 + c];
    }
    __syncthreads();
    #pragma unroll
    for (int i = 0; i < 4; i++) {
        int n = r0 + i * 8;
        dst[(size_t)(n0 + n) * K + k0 + c] = __float2bfloat16(t[c][n]);
    }
}

// ---------------- bf16 MFMA GEMM: C = A(MxK) @ Wt(NxK)^T + bias ------------
// Tile TMx64, BK=32, 4 waves. TM=128: wave has 2x4 MFMA tiles; TM=64: 1x4.
// xor k-slot swizzle keeps staging + b128 frag reads conflict-free.
// EPI 1: relu -> bf16 out. EPI 2: + res(fp32) -> fp32 out.
template <int TM, int EPI>
__global__ __launch_bounds__(256) void mfma_gemm(const __hip_bfloat16* __restrict__ A,
                                                 const __hip_bfloat16* __restrict__ Wt,
                                                 const float* __restrict__ bias,
                                                 const float* __restrict__ res,
                                                 float* __restrict__ Cf,
                                                 __hip_bfloat16* __restrict__ Cb,
                                                 int M, int Nn, int K) {
    constexpr int MF = TM / 64;
    __shared__ __align__(16) __hip_bfloat16 As[TM * 32];
    __shared__ __align__(16) __hip_bfloat16 Bs[64 * 32];
    const int tid = threadIdx.x, w = tid >> 6, lane = tid & 63;
    const int lm = lane & 15, lq = lane >> 4;
    const int bm = blockIdx.y * TM, bn = blockIdx.x * 64;
    f32x4 acc[MF][4];
    #pragma unroll
    for (int i = 0; i < MF; i++)
        #pragma unroll
        for (int j = 0; j < 4; j++) acc[i][j] = (f32x4){0.f, 0.f, 0.f, 0.f};

    const int sw = (lq ^ (lm & 3)) * 8;
    for (int k0 = 0; k0 < K; k0 += 32) {
        #pragma unroll
        for (int p = 0; p < MF; p++) {
            int c = p * 256 + tid;
            int r = c >> 2, gk = ((c & 3) ^ (r & 3)) * 8;
            gload16(A + (size_t)(bm + r) * K + k0 + gk, As + (p * 256 + w * 64) * 8);
        }
        {
            int r = tid >> 2, gk = ((tid & 3) ^ (r & 3)) * 8;
            gload16(Wt + (size_t)(bn + r) * K + k0 + gk, Bs + w * 512);
        }
        __syncthreads();
        short8 a[MF];
        #pragma unroll
        for (int mf = 0; mf < MF; mf++)
            a[mf] = *(const short8*)&As[(w * (TM / 4) + mf * 16 + lm) * 32 + sw];
        #pragma unroll
        for (int nf = 0; nf < 4; nf++) {
            short8 bfr = *(const short8*)&Bs[(nf * 16 + lm) * 32 + sw];
            #pragma unroll
            for (int mf = 0; mf < MF; mf++)
                acc[mf][nf] = __builtin_amdgcn_mfma_f32_16x16x32_bf16(a[mf], bfr, acc[mf][nf], 0, 0, 0);
        }
        __syncthreads();
    }
    #pragma unroll
    for (int nf = 0; nf < 4; nf++) {
        int cg = bn + nf * 16 + lm;
        float bi = bias[cg];
        #pragma unroll
        for (int mf = 0; mf < MF; mf++) {
            #pragma unroll
            for (int r = 0; r < 4; r++) {
                int rg = bm + w * (TM / 4) + mf * 16 + lq * 4 + r;
                float v = acc[mf][nf][r] + bi;
                if (EPI == 1) {
                    v = fmaxf(v, 0.f);
                    Cb[(size_t)rg * Nn + cg] = __float2bfloat16(v);
                } else {
                    v += res[(size_t)rg * Nn + cg];
                    Cf[(size_t)rg * Nn + cg] = v;
                }
            }
        }
    }
}

// ---------------- QKV fused: LN1 + GEMM + bias + RoPE + scatter ------------
// A = x (fp32); block computes LN stats for its 128 rows, stages normalized
// bf16 A-tiles manually; W staged via global_load_lds. q scaled by 1/sqrt(d).
// v written TRANSPOSED: vt[B,H,d,N] so attention reads V frags row-major.
__global__ __launch_bounds__(256) void qkv_fused(const float* __restrict__ x,
                                                 const __hip_bfloat16* __restrict__ Wt,
                                                 const float* __restrict__ bias,
                                                 const float* __restrict__ g,
                                                 const float* __restrict__ bvec,
                                                 const float* __restrict__ fcos,
                                                 const float* __restrict__ fsin,
                                                 __hip_bfloat16* __restrict__ qout,
                                                 __hip_bfloat16* __restrict__ kout,
                                                 __hip_bfloat16* __restrict__ vt) {
    const int K = 256;
    __shared__ __align__(16) __hip_bfloat16 As[128 * 32];
    __shared__ __align__(16) __hip_bfloat16 Bs[64 * 32];
    __shared__ float muS[128], rsS[128];
    const int tid = threadIdx.x, w = tid >> 6, lane = tid & 63;
    const int lm = lane & 15, lq = lane >> 4;
    const int bm = blockIdx.y * 128, bn = blockIdx.x * 64;

    // --- LN stats: wave w covers rows w*32..w*32+31, 4 rows per pass -------
    #pragma unroll
    for (int i = 0; i < 8; i++) {
        int r = w * 32 + i * 4 + (lane >> 4);
        const float* xr = x + (size_t)(bm + r) * 256 + (lane & 15) * 16;
        float s = 0.f, ss = 0.f;
        #pragma unroll
        for (int j = 0; j < 4; j++) {
            float4 v = *(const float4*)(xr + j * 4);
            s  += v.x + v.y + v.z + v.w;
            ss += v.x * v.x + v.y * v.y + v.z * v.z + v.w * v.w;
        }
        #pragma unroll
        for (int off = 1; off <= 8; off <<= 1) {
            s  += __shfl_xor(s, off);
            ss += __shfl_xor(ss, off);
        }
        if ((lane & 15) == 0) {
            float mu = s * (1.0f / 256.0f);
            muS[r] = mu;
            rsS[r] = rsqrtf(ss * (1.0f / 256.0f) - mu * mu + EPS_);
        }
    }
    __syncthreads();

    f32x4 acc[2][4];
    #pragma unroll
    for (int i = 0; i < 2; i++)
        #pragma unroll
        for (int j = 0; j < 4; j++) acc[i][j] = (f32x4){0.f, 0.f, 0.f, 0.f};

    const int sw = (lq ^ (lm & 3)) * 8;
    for (int k0 = 0; k0 < K; k0 += 32) {
        // A: normalize 2x8 fp32 -> bf16 into swizzled LDS
        short8 hbuf[2];
        int rr[2];
        #pragma unroll
        for (int p = 0; p < 2; p++) {
            int c = p * 256 + tid;
            int r = c >> 2, gk = ((c & 3) ^ (r & 3)) * 8;
            rr[p] = r;
            const float* src = x + (size_t)(bm + r) * 256 + k0 + gk;
            float4 f0 = *(const float4*)src;
            float4 f1 = *(const float4*)(src + 4);
            float4 g0 = *(const float4*)(g + k0 + gk);
            float4 g1 = *(const float4*)(g + k0 + gk + 4);
            float4 b0 = *(const float4*)(bvec + k0 + gk);
            float4 b1 = *(const float4*)(bvec + k0 + gk + 4);
            float mu = muS[r], rs = rsS[r];
            short8 h;
            h[0] = bf16s((f0.x - mu) * rs * g0.x + b0.x);
            h[1] = bf16s((f0.y - mu) * rs * g0.y + b0.y);
            h[2] = bf16s((f0.z - mu) * rs * g0.z + b0.z);
            h[3] = bf16s((f0.w - mu) * rs * g0.w + b0.w);
            h[4] = bf16s((f1.x - mu) * rs * g1.x + b1.x);
            h[5] = bf16s((f1.y - mu) * rs * g1.y + b1.y);
            h[6] = bf16s((f1.z - mu) * rs * g1.z + b1.z);
            h[7] = bf16s((f1.w - mu) * rs * g1.w + b1.w);
            hbuf[p] = h;
        }
        {
            int r = tid >> 2, gk = ((tid & 3) ^ (r & 3)) * 8;
            gload16(Wt + (size_t)(bn + r) * K + k0 + gk, Bs + w * 512);
        }
        #pragma unroll
        for (int p = 0; p < 2; p++) {
            int c = p * 256 + tid;
            *(short8*)&As[(rr[p] * 4 + (c & 3)) * 8] = hbuf[p];
        }
        __syncthreads();
        short8 a0 = *(const short8*)&As[(w * 32 + lm) * 32 + sw];
        short8 a1 = *(const short8*)&As[(w * 32 + 16 + lm) * 32 + sw];
        #pragma unroll
        for (int nf = 0; nf < 4; nf++) {
            short8 bfr = *(const short8*)&Bs[(nf * 16 + lm) * 32 + sw];
            acc[0][nf] = __builtin_amdgcn_mfma_f32_16x16x32_bf16(a0, bfr, acc[0][nf], 0, 0, 0);
            acc[1][nf] = __builtin_amdgcn_mfma_f32_16x16x32_bf16(a1, bfr, acc[1][nf], 0, 0, 0);
        }
        __syncthreads();
    }
    const int seg = bn >> 8;  // 0=q 1=k 2=v, uniform per block
    #pragma unroll
    for (int nf = 0; nf < 4; nf++) {
        int cg = bn + nf * 16 + lm;
        int hh = (cg & 255) >> 5;
        int dd = (nf & 1) * 16 + lm;
        int i0 = dd >> 1;
        float bi = bias[cg];
        #pragma unroll
        for (int mf = 0; mf < 2; mf++) {
            #pragma unroll
            for (int r = 0; r < 4; r++) {
                int rg = bm + w * 32 + mf * 16 + lq * 4 + r;
                int bb = rg >> 11, n = rg & (Nseq - 1);
                float v = acc[mf][nf][r] + bi;
                if (seg == 2) {
                    vt[(((size_t)(bb * Hh + hh)) * Hd + dd) * Nseq + n] = __float2bfloat16(v);
                } else {
                    float vp = __shfl_xor(v, 1);
                    float cs = fcos[n * 16 + i0], sn = fsin[n * 16 + i0];
                    float outv = (dd & 1) ? (vp * sn + v * cs) : (v * cs - vp * sn);
                    if (seg == 0) outv *= SCALE_;
                    __hip_bfloat16* dst = (seg == 0) ? qout : kout;
                    dst[(((size_t)(bb * Hh + hh)) * Nseq + n) * Hd + dd] = __float2bfloat16(outv);
                }
            }
        }
    }
}

// ---------------- FFN1 fused: LN2 + GEMM + relu -> bf16 --------------------
__global__ __launch_bounds__(256) void ffn1_fused(const float* __restrict__ x,
                                                  const __hip_bfloat16* __restrict__ Wt,
                                                  const float* __restrict__ bias,
                                                  const float* __restrict__ g,
                                                  const float* __restrict__ bvec,
                                                  __hip_bfloat16* __restrict__ Cb,
                                                  int Nn) {
    const int K = 256;
    __shared__ __align__(16) __hip_bfloat16 As[128 * 32];
    __shared__ __align__(16) __hip_bfloat16 Bs[64 * 32];
    __shared__ float muS[128], rsS[128];
    const int tid = threadIdx.x, w = tid >> 6, lane = tid & 63;
    const int lm = lane & 15, lq = lane >> 4;
    const int bm = blockIdx.y * 128, bn = blockIdx.x * 64;

    #pragma unroll
    for (int i = 0; i < 8; i++) {
        int r = w * 32 + i * 4 + (lane >> 4);
        const float* xr = x + (size_t)(bm + r) * 256 + (lane & 15) * 16;
        float s = 0.f, ss = 0.f;
        #pragma unroll
        for (int j = 0; j < 4; j++) {
            float4 v = *(const float4*)(xr + j * 4);
            s  += v.x + v.y + v.z + v.w;
            ss += v.x * v.x + v.y * v.y + v.z * v.z + v.w * v.w;
        }
        #pragma unroll
        for (int off = 1; off <= 8; off <<= 1) {
            s  += __shfl_xor(s, off);
            ss += __shfl_xor(ss, off);
        }
        if ((lane & 15) == 0) {
            float mu = s * (1.0f / 256.0f);
            muS[r] = mu;
            rsS[r] = rsqrtf(ss * (1.0f / 256.0f) - mu * mu + EPS_);
        }
    }
    __syncthreads();

    f32x4 acc[2][4];
    #pragma unroll
    for (int i = 0; i < 2; i++)
        #pragma unroll
        for (int j = 0; j < 4; j++) acc[i][j] = (f32x4){0.f, 0.f, 0.f, 0.f};

    const int sw = (lq ^ (lm & 3)) * 8;
    for (int k0 = 0; k0 < K; k0 += 32) {
        short8 hbuf[2];
        int rr[2];
        #pragma unroll
        for (int p = 0; p < 2; p++) {
            int c = p * 256 + tid;
            int r = c >> 2, gk = ((c & 3) ^ (r & 3)) * 8;
            rr[p] = r;
            const float* src = x + (size_t)(bm + r) * 256 + k0 + gk;
            float4 f0 = *(const float4*)src;
            float4 f1 = *(const float4*)(src + 4);
            float4 g0 = *(const float4*)(g + k0 + gk);
            float4 g1 = *(const float4*)(g + k0 + gk + 4);
            float4 b0 = *(const float4*)(bvec + k0 + gk);
            float4 b1 = *(const float4*)(bvec + k0 + gk + 4);
            float mu = muS[r], rs = rsS[r];
            short8 h;
            h[0] = bf16s((f0.x - mu) * rs * g0.x + b0.x);
            h[1] = bf16s((f0.y - mu) * rs * g0.y + b0.y);
            h[2] = bf16s((f0.z - mu) * rs * g0.z + b0.z);
            h[3] = bf16s((f0.w - mu) * rs * g0.w + b0.w);
            h[4] = bf16s((f1.x - mu) * rs * g1.x + b1.x);
            h[5] = bf16s((f1.y - mu) * rs * g1.y + b1.y);
            h[6] = bf16s((f1.z - mu) * rs * g1.z + b1.z);
            h[7] = bf16s((f1.w - mu) * rs * g1.w + b1.w);
            hbuf[p] = h;
        }
        {
            int r = tid >> 2, gk = ((tid & 3) ^ (r & 3)) * 8;
            gload16(Wt + (size_t)(bn + r) * K + k0 + gk, Bs + w * 512);
        }
        #pragma unroll
        for (int p = 0; p < 2; p++) {
            int c = p * 256 + tid;
            *(short8*)&As[(rr[p] * 4 + (c & 3)) * 8] = hbuf[p];
        }
        __syncthreads();
        short8 a0 = *(const short8*)&As[(w * 32 + lm) * 32 + sw];
        short8 a1 = *(const short8*)&As[(w * 32 + 16 + lm) * 32 + sw];
        #pragma unroll
        for (int nf = 0; nf < 4; nf++) {
            short8 bfr = *(const short8*)&Bs[(nf * 16 + lm) * 32 + sw];
            acc[0][nf] = __builtin_amdgcn_mfma_f32_16x16x32_bf16(a0, bfr, acc[0][nf], 0, 0, 0);
            acc[1][nf] = __builtin_amdgcn_mfma_f32_16x16x32_bf16(a1, bfr, acc[1][nf], 0, 0, 0);
        }
        __syncthreads();
    }
    #pragma unroll
    for (int nf = 0; nf < 4; nf++) {
        int cg = bn + nf * 16 + lm;
        float bi = bias[cg];
        #pragma unroll
        for (int mf = 0; mf < 2; mf++) {
            #pragma unroll
            for (int r = 0; r < 4; r++) {
                int rg = bm + w * 32 + mf * 16 + lq * 4 + r;
                float v = fmaxf(acc[mf][nf][r] + bi, 0.f);
                Cb[(size_t)rg * Nn + cg] = __float2bfloat16(v);
            }
        }
    }
}

// ---------------- Flash attention: K via async-LDS dbuf, V direct-to-reg ---
// grid (32, 32), 4 waves/block, 64 q rows. V is pre-transposed in global
// ([B,H,d,N]) so B-frags are row-major dwordx4 loads, register-prefetched one
// chunk ahead (L2-hot: 32 blocks share each head's K/V). No LDS V transpose.
__global__ __launch_bounds__(256) void attn_mfma(const __hip_bfloat16* __restrict__ q,
                                                 const __hip_bfloat16* __restrict__ k,
                                                 const __hip_bfloat16* __restrict__ vt,
                                                 __hip_bfloat16* __restrict__ att) {
    __shared__ __align__(16) __hip_bfloat16 Qs[64 * 32];
    __shared__ __align__(16) __hip_bfloat16 Ks[2][64 * 32];
    __shared__ __align__(16) __hip_bfloat16 Ps[4][16 * 68];
    const int tid = threadIdx.x, w = tid >> 6, lane = tid & 63;
    const int lm = lane & 15, lq = lane >> 4;
    const int bh = blockIdx.y, qbase = blockIdx.x * 64;
    const __hip_bfloat16* qp  = q + ((size_t)bh * Nseq + qbase) * Hd;
    const __hip_bfloat16* kp  = k + (size_t)bh * Nseq * Hd;
    const __hip_bfloat16* vr0 = vt + ((size_t)bh * Hd + lm) * Nseq + lq * 8;
    const __hip_bfloat16* vr1 = vr0 + 16 * Nseq;

    const int sr = tid >> 2, sgk = ((tid & 3) ^ (sr & 3)) * 8;
    gload16(qp + sr * 32 + sgk, Qs + w * 512);
    gload16(kp + sr * 32 + sgk, Ks[0] + w * 512);
    short8 v00 = *(const short8*)(vr0);
    short8 v01 = *(const short8*)(vr0 + 32);
    short8 v10 = *(const short8*)(vr1);
    short8 v11 = *(const short8*)(vr1 + 32);
    __syncthreads();

    const int sw = (lq ^ (lm & 3)) * 8;
    short8 qf = *(const short8*)&Qs[(w * 16 + lm) * 32 + sw];
    f32x4 O0 = {0.f, 0.f, 0.f, 0.f};
    f32x4 O1 = {0.f, 0.f, 0.f, 0.f};
    float sm[4] = {0.f, 0.f, 0.f, 0.f};

    for (int kt = 0; kt < Nseq / 64; kt++) {
        int cur = kt & 1;
        short8 n00, n01, n10, n11;
        if (kt + 1 < Nseq / 64) {
            gload16(kp + (size_t)(kt + 1) * 64 * 32 + sr * 32 + sgk, Ks[cur ^ 1] + w * 512);
            int kb = (kt + 1) * 64;
            n00 = *(const short8*)(vr0 + kb);
            n01 = *(const short8*)(vr0 + kb + 32);
            n10 = *(const short8*)(vr1 + kb);
            n11 = *(const short8*)(vr1 + kb + 32);
        }
        // S = (q*scale) K^T : 16 q rows x 64 keys per wave
        f32x4 S[4];
        #pragma unroll
        for (int kb = 0; kb < 4; kb++) {
            short8 kf = *(const short8*)&Ks[cur][(kb * 16 + lm) * 32 + sw];
            f32x4 zz = {0.f, 0.f, 0.f, 0.f};
            S[kb] = __builtin_amdgcn_mfma_f32_16x16x32_bf16(qf, kf, zz, 0, 0, 0);
        }
        #pragma unroll
        for (int kb = 0; kb < 4; kb++) {
            #pragma unroll
            for (int r = 0; r < 4; r++) {
                float p = __expf(S[kb][r]);
                sm[r] += p;
                Ps[w][(lq * 4 + r) * 68 + kb * 16 + lm] = __float2bfloat16(p);
            }
        }
        // O += P V  (P via per-wave LDS round trip, V frags already in regs)
        short8 pf0 = read8x2(&Ps[w][lm * 68 + lq * 8]);
        short8 pf1 = read8x2(&Ps[w][lm * 68 + 32 + lq * 8]);
        O0 = __builtin_amdgcn_mfma_f32_16x16x32_bf16(pf0, v00, O0, 0, 0, 0);
        O1 = __builtin_amdgcn_mfma_f32_16x16x32_bf16(pf0, v10, O1, 0, 0, 0);
        O0 = __builtin_amdgcn_mfma_f32_16x16x32_bf16(pf1, v01, O0, 0, 0, 0);
        O1 = __builtin_amdgcn_mfma_f32_16x16x32_bf16(pf1, v11, O1, 0, 0, 0);
        v00 = n00; v01 = n01; v10 = n10; v11 = n11;
        __syncthreads();  // K dbuf handoff (also drains gload vmcnt)
    }
    #pragma unroll
    for (int off = 1; off <= 8; off <<= 1) {
        #pragma unroll
        for (int r = 0; r < 4; r++) sm[r] += __shfl_xor(sm[r], off);
    }
    const int bb = bh >> 3, hh = bh & 7;
    #pragma unroll
    for (int r = 0; r < 4; r++) {
        float inv = 1.0f / sm[r];
        int n = qbase + w * 16 + lq * 4 + r;
        __hip_bfloat16* op = att + ((size_t)(bb * Nseq + n)) * Dm + hh * Hd;
        op[lm]      = __float2bfloat16(O0[r] * inv);
        op[16 + lm] = __float2bfloat16(O1[r] * inv);
    }
}

extern "C" void kernel_launch(void* const* d_in, const int* in_sizes, int n_in,
                              void* d_out, int out_size, void* d_ws, size_t ws_size,
                              hipStream_t stream) {
    const float* x      = (const float*)d_in[0];
    const float* fcos   = (const float*)d_in[1];
    const float* fsin   = (const float*)d_in[2];
    const float* w_qkv  = (const float*)d_in[3];
    const float* b_qkv  = (const float*)d_in[4];
    const float* w_proj = (const float*)d_in[5];
    const float* b_proj = (const float*)d_in[6];
    const float* ln1_g  = (const float*)d_in[7];
    const float* ln1_b  = (const float*)d_in[8];
    const float* ln2_g  = (const float*)d_in[9];
    const float* ln2_b  = (const float*)d_in[10];
    const float* w1     = (const float*)d_in[11];
    const float* b1     = (const float*)d_in[12];
    const float* w2     = (const float*)d_in[13];
    const float* b2     = (const float*)d_in[14];
    float* out = (float*)d_out;
    char* base = (char*)d_ws;
    const size_t MB = (size_t)1 << 20;

    __hip_bfloat16* qb  = (__hip_bfloat16*)(base);            // 4 MB
    __hip_bfloat16* kbf = (__hip_bfloat16*)(base + 4 * MB);   // 4 MB
    __hip_bfloat16* vtb = (__hip_bfloat16*)(base + 8 * MB);   // 4 MB (transposed)
    __hip_bfloat16* att = (__hip_bfloat16*)(base + 12 * MB);  // 4 MB
    float*          x2f = (float*)(base + 16 * MB);           // 8 MB
    __hip_bfloat16* ffn = (__hip_bfloat16*)(base + 24 * MB);  // 8 MB
    __hip_bfloat16* wqT = (__hip_bfloat16*)(base + 32 * MB);            // 768x256
    __hip_bfloat16* wpT = (__hip_bfloat16*)(base + 32 * MB + 393216);   // 256x256
    __hip_bfloat16* w1T = (__hip_bfloat16*)(base + 32 * MB + 524288);   // 512x256
    __hip_bfloat16* w2T = (__hip_bfloat16*)(base + 32 * MB + 786432);   // 256x512

    const int rows = Bsz * Nseq;  // 8192

    wconv_kernel<<<512, 256, 0, stream>>>(w_qkv, w_proj, w1, w2, wqT, wpT, w1T, w2T);
    qkv_fused<<<dim3(12, 64), 256, 0, stream>>>(x, wqT, b_qkv, ln1_g, ln1_b, fcos, fsin,
                                                qb, kbf, vtb);
    attn_mfma<<<dim3(Nseq / 64, Bsz * Hh), 256, 0, stream>>>(qb, kbf, vtb, att);
    mfma_gemm<64, 2><<<dim3(4, 128), 256, 0, stream>>>(att, wpT, b_proj, x, x2f, nullptr,
                                                       rows, 256, 256);
    ffn1_fused<<<dim3(8, 64), 256, 0, stream>>>(x2f, w1T, b1, ln2_g, ln2_b, ffn, 512);
    mfma_gemm<64, 2><<<dim3(4, 128), 256, 0, stream>>>(ffn, w2T, b2, x2f, out,
                                                       nullptr, rows, 256, 512);
}

// Round 5
// 205.044 us; speedup vs baseline: 1.1233x; 1.1233x over previous
//
#include <hip/hip_runtime.h>
#include <hip/hip_bf16.h>
#include <math.h>

#define Bsz 4
#define Nseq 2048
#define Dm 256
#define Hh 8
#define Hd 32
#define EPS_ 1e-5f
#define SCALE_ 0.17677669529663687f               // 1/sqrt(32)
#define QSC_ (0.17677669529663687f * 1.4426950408889634f)  // fold log2(e) for exp2

typedef __attribute__((ext_vector_type(8))) short short8;
typedef __attribute__((ext_vector_type(4))) short short4v;
typedef __attribute__((ext_vector_type(4))) float f32x4;
typedef __attribute__((ext_vector_type(16))) float f32x16;

// async global->LDS, 16B per lane. LDS dest = wave-uniform base + lane*16.
__device__ __forceinline__ void gload16(const void* g, void* l) {
    __builtin_amdgcn_global_load_lds(
        (const __attribute__((address_space(1))) void*)g,
        (__attribute__((address_space(3))) void*)l, 16, 0, 0);
}

__device__ __forceinline__ short bf16s(float f) {
    __hip_bfloat16 h = __float2bfloat16(f);
    return *(short*)&h;
}

__device__ __forceinline__ int pkbf(float a, float b) {
    __hip_bfloat16 lo = __float2bfloat16(a), hi2 = __float2bfloat16(b);
    return (int)(((unsigned int)*(unsigned short*)&hi2 << 16) |
                 (unsigned int)*(unsigned short*)&lo);
}

union I4S8 { int i[4]; short8 s; };

// ---------------- LayerNorm: one wave per row, bf16 output -----------------
__global__ __launch_bounds__(256) void ln_kernel(const float* __restrict__ x,
                                                 const float* __restrict__ g,
                                                 const float* __restrict__ b,
                                                 __hip_bfloat16* __restrict__ out) {
    int row  = blockIdx.x * 4 + (threadIdx.x >> 6);
    int lane = threadIdx.x & 63;
    const float* xr = x + (size_t)row * Dm;
    float4 v = *(const float4*)(xr + lane * 4);
    float s  = v.x + v.y + v.z + v.w;
    float ss = v.x * v.x + v.y * v.y + v.z * v.z + v.w * v.w;
    #pragma unroll
    for (int off = 32; off; off >>= 1) {
        s  += __shfl_xor(s, off);
        ss += __shfl_xor(ss, off);
    }
    float mu  = s * (1.0f / Dm);
    float var = ss * (1.0f / Dm) - mu * mu;
    float rs  = rsqrtf(var + EPS_);
    float4 gv = *(const float4*)(g + lane * 4);
    float4 bv = *(const float4*)(b + lane * 4);
    short4v o4 = { bf16s((v.x - mu) * rs * gv.x + bv.x),
                   bf16s((v.y - mu) * rs * gv.y + bv.y),
                   bf16s((v.z - mu) * rs * gv.z + bv.z),
                   bf16s((v.w - mu) * rs * gv.w + bv.w) };
    *(short4v*)(out + (size_t)row * Dm + lane * 4) = o4;
}

// ---------------- Weight transpose+convert: fp32 [K][N] -> bf16 [N][K] -----
__global__ __launch_bounds__(256) void wconv_kernel(
    const float* __restrict__ s0, const float* __restrict__ s1,
    const float* __restrict__ s2, const float* __restrict__ s3,
    __hip_bfloat16* __restrict__ d0, __hip_bfloat16* __restrict__ d1,
    __hip_bfloat16* __restrict__ d2, __hip_bfloat16* __restrict__ d3) {
    __shared__ float t[32][33];
    int bid = blockIdx.x;
    const float* src; __hip_bfloat16* dst; int K, N, tb;
    if (bid < 192)      { src = s0; dst = d0; K = 256; N = 768; tb = bid; }
    else if (bid < 256) { src = s1; dst = d1; K = 256; N = 256; tb = bid - 192; }
    else if (bid < 384) { src = s2; dst = d2; K = 256; N = 512; tb = bid - 256; }
    else                { src = s3; dst = d3; K = 512; N = 256; tb = bid - 384; }
    int tn = N >> 5;
    int k0 = (tb / tn) * 32, n0 = (tb % tn) * 32;
    int c = threadIdx.x & 31, r0 = threadIdx.x >> 5;
    #pragma unroll
    for (int i = 0; i < 4; i++) {
        int r = r0 + i * 8;
        t[r][c] = src[(size_t)(k0 + r) * N + n0 + c];
    }
    __syncthreads();
    #pragma unroll
    for (int i = 0; i < 4; i++) {
        int n = r0 + i * 8;
        dst[(size_t)(n0 + n) * K + k0 + c] = __float2bfloat16(t[c][n]);
    }
}

// ---------------- bf16 MFMA GEMM: C = A(MxK) @ Wt(NxK)^T + bias ------------
template <int TM, int EPI>
__global__ __launch_bounds__(256) void mfma_gemm(const __hip_bfloat16* __restrict__ A,
                                                 const __hip_bfloat16* __restrict__ Wt,
                                                 const float* __restrict__ bias,
                                                 const float* __restrict__ res,
                                                 float* __restrict__ Cf,
                                                 __hip_bfloat16* __restrict__ Cb,
                                                 int M, int Nn, int K) {
    constexpr int MF = TM / 64;
    __shared__ __align__(16) __hip_bfloat16 As[TM * 32];
    __shared__ __align__(16) __hip_bfloat16 Bs[64 * 32];
    const int tid = threadIdx.x, w = tid >> 6, lane = tid & 63;
    const int lm = lane & 15, lq = lane >> 4;
    const int bm = blockIdx.y * TM, bn = blockIdx.x * 64;
    f32x4 acc[MF][4];
    #pragma unroll
    for (int i = 0; i < MF; i++)
        #pragma unroll
        for (int j = 0; j < 4; j++) acc[i][j] = (f32x4){0.f, 0.f, 0.f, 0.f};

    const int sw = (lq ^ (lm & 3)) * 8;
    for (int k0 = 0; k0 < K; k0 += 32) {
        #pragma unroll
        for (int p = 0; p < MF; p++) {
            int c = p * 256 + tid;
            int r = c >> 2, gk = ((c & 3) ^ (r & 3)) * 8;
            gload16(A + (size_t)(bm + r) * K + k0 + gk, As + (p * 256 + w * 64) * 8);
        }
        {
            int r = tid >> 2, gk = ((tid & 3) ^ (r & 3)) * 8;
            gload16(Wt + (size_t)(bn + r) * K + k0 + gk, Bs + w * 512);
        }
        __syncthreads();
        short8 a[MF];
        #pragma unroll
        for (int mf = 0; mf < MF; mf++)
            a[mf] = *(const short8*)&As[(w * (TM / 4) + mf * 16 + lm) * 32 + sw];
        #pragma unroll
        for (int nf = 0; nf < 4; nf++) {
            short8 bfr = *(const short8*)&Bs[(nf * 16 + lm) * 32 + sw];
            #pragma unroll
            for (int mf = 0; mf < MF; mf++)
                acc[mf][nf] = __builtin_amdgcn_mfma_f32_16x16x32_bf16(a[mf], bfr, acc[mf][nf], 0, 0, 0);
        }
        __syncthreads();
    }
    #pragma unroll
    for (int nf = 0; nf < 4; nf++) {
        int cg = bn + nf * 16 + lm;
        float bi = bias[cg];
        #pragma unroll
        for (int mf = 0; mf < MF; mf++) {
            #pragma unroll
            for (int r = 0; r < 4; r++) {
                int rg = bm + w * (TM / 4) + mf * 16 + lq * 4 + r;
                float v = acc[mf][nf][r] + bi;
                if (EPI == 1) {
                    v = fmaxf(v, 0.f);
                    Cb[(size_t)rg * Nn + cg] = __float2bfloat16(v);
                } else {
                    v += res[(size_t)rg * Nn + cg];
                    Cf[(size_t)rg * Nn + cg] = v;
                }
            }
        }
    }
}

// ---------------- QKV: bf16 MFMA GEMM + bias + RoPE + scatter --------------
// q pre-scaled by (1/sqrt(d))*log2(e) (attn uses exp2). v written TRANSPOSED
// vt[B,H,d,N] so attention can stage V tiles with zero-transpose async loads.
__global__ __launch_bounds__(256) void qkv_mfma(const __hip_bfloat16* __restrict__ A,
                                                const __hip_bfloat16* __restrict__ Wt,
                                                const float* __restrict__ bias,
                                                const float* __restrict__ fcos,
                                                const float* __restrict__ fsin,
                                                __hip_bfloat16* __restrict__ qout,
                                                __hip_bfloat16* __restrict__ kout,
                                                __hip_bfloat16* __restrict__ vt) {
    const int K = 256, Nn = 768;
    __shared__ __align__(16) __hip_bfloat16 As[128 * 32];
    __shared__ __align__(16) __hip_bfloat16 Bs[64 * 32];
    const int tid = threadIdx.x, w = tid >> 6, lane = tid & 63;
    const int lm = lane & 15, lq = lane >> 4;
    const int bm = blockIdx.y * 128, bn = blockIdx.x * 64;
    f32x4 acc[2][4];
    #pragma unroll
    for (int i = 0; i < 2; i++)
        #pragma unroll
        for (int j = 0; j < 4; j++) acc[i][j] = (f32x4){0.f, 0.f, 0.f, 0.f};

    const int sw = (lq ^ (lm & 3)) * 8;
    for (int k0 = 0; k0 < K; k0 += 32) {
        #pragma unroll
        for (int p = 0; p < 2; p++) {
            int c = p * 256 + tid;
            int r = c >> 2, gk = ((c & 3) ^ (r & 3)) * 8;
            gload16(A + (size_t)(bm + r) * K + k0 + gk, As + (p * 256 + w * 64) * 8);
        }
        {
            int r = tid >> 2, gk = ((tid & 3) ^ (r & 3)) * 8;
            gload16(Wt + (size_t)(bn + r) * K + k0 + gk, Bs + w * 512);
        }
        __syncthreads();
        short8 a0 = *(const short8*)&As[(w * 32 + lm) * 32 + sw];
        short8 a1 = *(const short8*)&As[(w * 32 + 16 + lm) * 32 + sw];
        #pragma unroll
        for (int nf = 0; nf < 4; nf++) {
            short8 bfr = *(const short8*)&Bs[(nf * 16 + lm) * 32 + sw];
            acc[0][nf] = __builtin_amdgcn_mfma_f32_16x16x32_bf16(a0, bfr, acc[0][nf], 0, 0, 0);
            acc[1][nf] = __builtin_amdgcn_mfma_f32_16x16x32_bf16(a1, bfr, acc[1][nf], 0, 0, 0);
        }
        __syncthreads();
    }
    const int seg = bn >> 8;  // 0=q 1=k 2=v, uniform per block
    #pragma unroll
    for (int nf = 0; nf < 4; nf++) {
        int cg = bn + nf * 16 + lm;
        int hh = (cg & 255) >> 5;
        int dd = (nf & 1) * 16 + lm;
        int i0 = dd >> 1;
        float bi = bias[cg];
        #pragma unroll
        for (int mf = 0; mf < 2; mf++) {
            #pragma unroll
            for (int r = 0; r < 4; r++) {
                int rg = bm + w * 32 + mf * 16 + lq * 4 + r;
                int bb = rg >> 11, n = rg & (Nseq - 1);
                float v = acc[mf][nf][r] + bi;
                if (seg == 2) {
                    vt[(((size_t)(bb * Hh + hh)) * Hd + dd) * Nseq + n] = __float2bfloat16(v);
                } else {
                    float vp = __shfl_xor(v, 1);
                    float cs = fcos[n * 16 + i0], sn = fsin[n * 16 + i0];
                    float outv = (dd & 1) ? (vp * sn + v * cs) : (v * cs - vp * sn);
                    if (seg == 0) outv *= QSC_;
                    __hip_bfloat16* dst = (seg == 0) ? qout : kout;
                    dst[(((size_t)(bb * Hh + hh)) * Nseq + n) * Hd + dd] = __float2bfloat16(outv);
                }
            }
        }
    }
}

// ---------------- Flash attention: 32x32x16 MFMA, register P-transpose -----
// Wave handles 32 q rows x 64-key chunks. S^T = K·Q^T (C: row=key,col=q) so
// P reaches PV's A-operand layout via in-register pack + shfl_xor(32) only —
// no P LDS round trip. All staging via global_load_lds with xor-slot swizzles
// (bank-checked 2-way = free). q pre-scaled by SCALE*log2e -> exp2.
__global__ __launch_bounds__(256) void attn_mfma(const __hip_bfloat16* __restrict__ q,
                                                 const __hip_bfloat16* __restrict__ k,
                                                 const __hip_bfloat16* __restrict__ vt,
                                                 __hip_bfloat16* __restrict__ att) {
    __shared__ __align__(16) __hip_bfloat16 Qs[128 * 32];
    __shared__ __align__(16) __hip_bfloat16 Ks[2][32 * 64];  // pair-packed [key>>1][(key&1)*32+d]
    __shared__ __align__(16) __hip_bfloat16 Vs[2][32 * 64];  // [d][key], 8-slot swz
    __shared__ float smS[4][32];
    const int tid = threadIdx.x, w = tid >> 6;
    const int lane = tid & 63, l31 = lane & 31, hi = lane >> 5;
    const int bh = blockIdx.y, qbase = blockIdx.x * 128;
    const __hip_bfloat16* qp = q + ((size_t)bh * Nseq + qbase) * Hd;
    const __hip_bfloat16* kp = k + (size_t)bh * Nseq * Hd;
    const __hip_bfloat16* vp = vt + (size_t)bh * Hd * Nseq;

    const int r8 = tid >> 3, s8 = tid & 7;
    // Q: 128 rows x 32, 4-slot xor swizzle (2 rounds)
    #pragma unroll
    for (int p = 0; p < 2; p++) {
        int c = p * 256 + tid, r = c >> 2, sl = c & 3;
        gload16(qp + r * 32 + ((sl ^ (r & 3)) * 8), Qs + (p * 256 + w * 64) * 8);
    }
    // K/V chunk 0
    gload16(kp + (2 * r8 + (s8 >> 2)) * 32 + (((s8 & 3) ^ (r8 & 3)) * 8), Ks[0] + w * 512);
    gload16(vp + (size_t)r8 * Nseq + ((s8 ^ (r8 & 7)) * 8), Vs[0] + w * 512);
    __syncthreads();

    const int qrow = w * 32 + l31;
    short8 qf0 = *(const short8*)&Qs[qrow * 32 + ((hi ^ (l31 & 3)) * 8)];
    short8 qf1 = *(const short8*)&Qs[qrow * 32 + (((2 + hi) ^ (l31 & 3)) * 8)];

    f32x16 O;
    #pragma unroll
    for (int i = 0; i < 16; i++) O[i] = 0.f;
    float sm = 0.f;

    for (int kt = 0; kt < Nseq / 64; kt++) {
        const int cur = kt & 1;
        if (kt + 1 < Nseq / 64) {
            gload16(kp + ((kt + 1) * 64 + 2 * r8 + (s8 >> 2)) * 32 + (((s8 & 3) ^ (r8 & 3)) * 8),
                    Ks[cur ^ 1] + w * 512);
            gload16(vp + (size_t)r8 * Nseq + (kt + 1) * 64 + ((s8 ^ (r8 & 7)) * 8),
                    Vs[cur ^ 1] + w * 512);
        }
        // S^T[key][q] per kb (32 keys), accumulated over 2 d-slices
        f32x16 St0, St1;
        #pragma unroll
        for (int i = 0; i < 16; i++) { St0[i] = 0.f; St1[i] = 0.f; }
        {
            int prow = l31 >> 1;
            int elb = prow * 64 + (l31 & 1) * 32;
            short8 kf0 = *(const short8*)&Ks[cur][elb + ((hi ^ (prow & 3)) * 8)];
            short8 kf1 = *(const short8*)&Ks[cur][elb + (((2 + hi) ^ (prow & 3)) * 8)];
            St0 = __builtin_amdgcn_mfma_f32_32x32x16_bf16(kf0, qf0, St0, 0, 0, 0);
            St0 = __builtin_amdgcn_mfma_f32_32x32x16_bf16(kf1, qf1, St0, 0, 0, 0);
        }
        {
            int prow = 16 + (l31 >> 1);
            int elb = prow * 64 + (l31 & 1) * 32;
            short8 kf0 = *(const short8*)&Ks[cur][elb + ((hi ^ (prow & 3)) * 8)];
            short8 kf1 = *(const short8*)&Ks[cur][elb + (((2 + hi) ^ (prow & 3)) * 8)];
            St1 = __builtin_amdgcn_mfma_f32_32x32x16_bf16(kf0, qf0, St1, 0, 0, 0);
            St1 = __builtin_amdgcn_mfma_f32_32x32x16_bf16(kf1, qf1, St1, 0, 0, 0);
        }
        // exp2 + pack pairs (regs 2p,2p+1 are consecutive keys)
        int pk0[8], pk1[8];
        #pragma unroll
        for (int p = 0; p < 8; p++) {
            float a = exp2f(St0[2 * p]), b = exp2f(St0[2 * p + 1]);
            sm += a + b;
            pk0[p] = pkbf(a, b);
        }
        #pragma unroll
        for (int p = 0; p < 8; p++) {
            float a = exp2f(St1[2 * p]), b = exp2f(St1[2 * p + 1]);
            sm += a + b;
            pk1[p] = pkbf(a, b);
        }
        // PV: per 16-key block t, build P A-frag via reg-select + half-swap
        #pragma unroll
        for (int t = 0; t < 4; t++) {
            const int* PK = (t >> 1) ? pk1 : pk0;
            const int base = 4 * (t & 1);
            int keep0 = hi ? PK[base + 2] : PK[base + 0];
            int keep1 = hi ? PK[base + 3] : PK[base + 1];
            int send0 = hi ? PK[base + 0] : PK[base + 2];
            int send1 = hi ? PK[base + 1] : PK[base + 3];
            int x0 = __shfl_xor(send0, 32);
            int x1 = __shfl_xor(send1, 32);
            I4S8 u;
            u.i[0] = hi ? x0 : keep0;
            u.i[1] = hi ? x1 : keep1;
            u.i[2] = hi ? keep0 : x0;
            u.i[3] = hi ? keep1 : x1;
            short8 vf = *(const short8*)&Vs[cur][l31 * 64 + (((2 * t + hi) ^ (l31 & 7)) * 8)];
            O = __builtin_amdgcn_mfma_f32_32x32x16_bf16(u.s, vf, O, 0, 0, 0);
        }
        __syncthreads();
    }
    // column-pair sum over both halves; broadcast per-row denominators via LDS
    sm += __shfl_xor(sm, 32);
    if (hi == 0) smS[w][l31] = sm;
    __syncthreads();
    const int bb = bh >> 3, hh = bh & 7;
    #pragma unroll
    for (int m = 0; m < 4; m++) {
        float4 sv = *(const float4*)&smS[w][8 * m + 4 * hi];
        #pragma unroll
        for (int i = 0; i < 4; i++) {
            int n = qbase + w * 32 + 8 * m + 4 * hi + i;
            att[((size_t)(bb * Nseq + n)) * Dm + hh * Hd + l31] =
                __float2bfloat16(O[4 * m + i] * (1.0f / sv[i]));
        }
    }
}

extern "C" void kernel_launch(void* const* d_in, const int* in_sizes, int n_in,
                              void* d_out, int out_size, void* d_ws, size_t ws_size,
                              hipStream_t stream) {
    const float* x      = (const float*)d_in[0];
    const float* fcos   = (const float*)d_in[1];
    const float* fsin   = (const float*)d_in[2];
    const float* w_qkv  = (const float*)d_in[3];
    const float* b_qkv  = (const float*)d_in[4];
    const float* w_proj = (const float*)d_in[5];
    const float* b_proj = (const float*)d_in[6];
    const float* ln1_g  = (const float*)d_in[7];
    const float* ln1_b  = (const float*)d_in[8];
    const float* ln2_g  = (const float*)d_in[9];
    const float* ln2_b  = (const float*)d_in[10];
    const float* w1     = (const float*)d_in[11];
    const float* b1     = (const float*)d_in[12];
    const float* w2     = (const float*)d_in[13];
    const float* b2     = (const float*)d_in[14];
    float* out = (float*)d_out;
    char* base = (char*)d_ws;
    const size_t MB = (size_t)1 << 20;

    __hip_bfloat16* h   = (__hip_bfloat16*)(base);            // 4 MB (dead after qkv)
    __hip_bfloat16* qb  = (__hip_bfloat16*)(base + 4 * MB);
    __hip_bfloat16* kbf = (__hip_bfloat16*)(base + 8 * MB);
    __hip_bfloat16* vtb = (__hip_bfloat16*)(base + 12 * MB);  // transposed [B,H,d,N]
    __hip_bfloat16* att = (__hip_bfloat16*)(base + 16 * MB);
    float*          x2f = (float*)(base + 20 * MB);           // 8 MB
    __hip_bfloat16* h2  = (__hip_bfloat16*)(base);            // reuse h slot
    __hip_bfloat16* ffn = (__hip_bfloat16*)(base + 28 * MB);  // 8 MB
    __hip_bfloat16* wqT = (__hip_bfloat16*)(base + 40 * MB);            // 768x256
    __hip_bfloat16* wpT = (__hip_bfloat16*)(base + 40 * MB + 393216);   // 256x256
    __hip_bfloat16* w1T = (__hip_bfloat16*)(base + 40 * MB + 524288);   // 512x256
    __hip_bfloat16* w2T = (__hip_bfloat16*)(base + 40 * MB + 786432);   // 256x512

    const int rows = Bsz * Nseq;  // 8192

    wconv_kernel<<<512, 256, 0, stream>>>(w_qkv, w_proj, w1, w2, wqT, wpT, w1T, w2T);
    ln_kernel<<<rows / 4, 256, 0, stream>>>(x, ln1_g, ln1_b, h);
    qkv_mfma<<<dim3(12, 64), 256, 0, stream>>>(h, wqT, b_qkv, fcos, fsin, qb, kbf, vtb);
    attn_mfma<<<dim3(Nseq / 128, Bsz * Hh), 256, 0, stream>>>(qb, kbf, vtb, att);
    mfma_gemm<64, 2><<<dim3(4, 128), 256, 0, stream>>>(att, wpT, b_proj, x, x2f, nullptr,
                                                       rows, 256, 256);
    ln_kernel<<<rows / 4, 256, 0, stream>>>(x2f, ln2_g, ln2_b, h2);
    mfma_gemm<128, 1><<<dim3(8, 64), 256, 0, stream>>>(h2, w1T, b1, nullptr, nullptr, ffn,
                                                       rows, 512, 256);
    mfma_gemm<64, 2><<<dim3(4, 128), 256, 0, stream>>>(ffn, w2T, b2, x2f, out, nullptr,
                                                       rows, 256, 512);
}

// Round 6
// 184.474 us; speedup vs baseline: 1.2485x; 1.1115x over previous
//
#include <hip/hip_runtime.h>
#include <hip/hip_bf16.h>
#include <math.h>

#define Bsz 4
#define Nseq 2048
#define Dm 256
#define Hh 8
#define Hd 32
#define EPS_ 1e-5f
#define SCALE_ 0.17677669529663687f               // 1/sqrt(32)
#define QSC_ (0.17677669529663687f * 1.4426950408889634f)  // fold log2(e) for exp2

typedef __attribute__((ext_vector_type(8))) short short8;
typedef __attribute__((ext_vector_type(4))) short short4v;
typedef __attribute__((ext_vector_type(4))) float f32x4;
typedef __attribute__((ext_vector_type(16))) float f32x16;

// async global->LDS, 16B per lane. LDS dest = wave-uniform base + lane*16.
__device__ __forceinline__ void gload16(const void* g, void* l) {
    __builtin_amdgcn_global_load_lds(
        (const __attribute__((address_space(1))) void*)g,
        (__attribute__((address_space(3))) void*)l, 16, 0, 0);
}

__device__ __forceinline__ short bf16s(float f) {
    __hip_bfloat16 h = __float2bfloat16(f);
    return *(short*)&h;
}

union FU { float f; unsigned u; };

// pack two fp32 -> (bf16(a) | bf16(b)<<16) via single v_perm_b32 (truncation)
__device__ __forceinline__ int pk2bf(float a, float b) {
    FU ua, ub; ua.f = a; ub.f = b;
    return (int)__builtin_amdgcn_perm(ub.u, ua.u, 0x07060302u);
}

union I4S8 { int i[4]; short8 s; };

// ---------------- LayerNorm: one wave per row, bf16 output -----------------
__global__ __launch_bounds__(256) void ln_kernel(const float* __restrict__ x,
                                                 const float* __restrict__ g,
                                                 const float* __restrict__ b,
                                                 __hip_bfloat16* __restrict__ out) {
    int row  = blockIdx.x * 4 + (threadIdx.x >> 6);
    int lane = threadIdx.x & 63;
    const float* xr = x + (size_t)row * Dm;
    float4 v = *(const float4*)(xr + lane * 4);
    float s  = v.x + v.y + v.z + v.w;
    float ss = v.x * v.x + v.y * v.y + v.z * v.z + v.w * v.w;
    #pragma unroll
    for (int off = 32; off; off >>= 1) {
        s  += __shfl_xor(s, off);
        ss += __shfl_xor(ss, off);
    }
    float mu  = s * (1.0f / Dm);
    float var = ss * (1.0f / Dm) - mu * mu;
    float rs  = rsqrtf(var + EPS_);
    float4 gv = *(const float4*)(g + lane * 4);
    float4 bv = *(const float4*)(b + lane * 4);
    short4v o4 = { bf16s((v.x - mu) * rs * gv.x + bv.x),
                   bf16s((v.y - mu) * rs * gv.y + bv.y),
                   bf16s((v.z - mu) * rs * gv.z + bv.z),
                   bf16s((v.w - mu) * rs * gv.w + bv.w) };
    *(short4v*)(out + (size_t)row * Dm + lane * 4) = o4;
}

// ---------------- Weight transpose+convert: fp32 [K][N] -> bf16 [N][K] -----
__global__ __launch_bounds__(256) void wconv_kernel(
    const float* __restrict__ s0, const float* __restrict__ s1,
    const float* __restrict__ s2, const float* __restrict__ s3,
    __hip_bfloat16* __restrict__ d0, __hip_bfloat16* __restrict__ d1,
    __hip_bfloat16* __restrict__ d2, __hip_bfloat16* __restrict__ d3) {
    __shared__ float t[32][33];
    int bid = blockIdx.x;
    const float* src; __hip_bfloat16* dst; int K, N, tb;
    if (bid < 192)      { src = s0; dst = d0; K = 256; N = 768; tb = bid; }
    else if (bid < 256) { src = s1; dst = d1; K = 256; N = 256; tb = bid - 192; }
    else if (bid < 384) { src = s2; dst = d2; K = 256; N = 512; tb = bid - 256; }
    else                { src = s3; dst = d3; K = 512; N = 256; tb = bid - 384; }
    int tn = N >> 5;
    int k0 = (tb / tn) * 32, n0 = (tb % tn) * 32;
    int c = threadIdx.x & 31, r0 = threadIdx.x >> 5;
    #pragma unroll
    for (int i = 0; i < 4; i++) {
        int r = r0 + i * 8;
        t[r][c] = src[(size_t)(k0 + r) * N + n0 + c];
    }
    __syncthreads();
    #pragma unroll
    for (int i = 0; i < 4; i++) {
        int n = r0 + i * 8;
        dst[(size_t)(n0 + n) * K + k0 + c] = __float2bfloat16(t[c][n]);
    }
}

// ---------------- bf16 MFMA GEMM: C = A(MxK) @ Wt(NxK)^T + bias ------------
template <int TM, int EPI>
__global__ __launch_bounds__(256) void mfma_gemm(const __hip_bfloat16* __restrict__ A,
                                                 const __hip_bfloat16* __restrict__ Wt,
                                                 const float* __restrict__ bias,
                                                 const float* __restrict__ res,
                                                 float* __restrict__ Cf,
                                                 __hip_bfloat16* __restrict__ Cb,
                                                 int M, int Nn, int K) {
    constexpr int MF = TM / 64;
    __shared__ __align__(16) __hip_bfloat16 As[TM * 32];
    __shared__ __align__(16) __hip_bfloat16 Bs[64 * 32];
    const int tid = threadIdx.x, w = tid >> 6, lane = tid & 63;
    const int lm = lane & 15, lq = lane >> 4;
    const int bm = blockIdx.y * TM, bn = blockIdx.x * 64;
    f32x4 acc[MF][4];
    #pragma unroll
    for (int i = 0; i < MF; i++)
        #pragma unroll
        for (int j = 0; j < 4; j++) acc[i][j] = (f32x4){0.f, 0.f, 0.f, 0.f};

    const int sw = (lq ^ (lm & 3)) * 8;
    for (int k0 = 0; k0 < K; k0 += 32) {
        #pragma unroll
        for (int p = 0; p < MF; p++) {
            int c = p * 256 + tid;
            int r = c >> 2, gk = ((c & 3) ^ (r & 3)) * 8;
            gload16(A + (size_t)(bm + r) * K + k0 + gk, As + (p * 256 + w * 64) * 8);
        }
        {
            int r = tid >> 2, gk = ((tid & 3) ^ (r & 3)) * 8;
            gload16(Wt + (size_t)(bn + r) * K + k0 + gk, Bs + w * 512);
        }
        __syncthreads();
        short8 a[MF];
        #pragma unroll
        for (int mf = 0; mf < MF; mf++)
            a[mf] = *(const short8*)&As[(w * (TM / 4) + mf * 16 + lm) * 32 + sw];
        #pragma unroll
        for (int nf = 0; nf < 4; nf++) {
            short8 bfr = *(const short8*)&Bs[(nf * 16 + lm) * 32 + sw];
            #pragma unroll
            for (int mf = 0; mf < MF; mf++)
                acc[mf][nf] = __builtin_amdgcn_mfma_f32_16x16x32_bf16(a[mf], bfr, acc[mf][nf], 0, 0, 0);
        }
        __syncthreads();
    }
    #pragma unroll
    for (int nf = 0; nf < 4; nf++) {
        int cg = bn + nf * 16 + lm;
        float bi = bias[cg];
        #pragma unroll
        for (int mf = 0; mf < MF; mf++) {
            #pragma unroll
            for (int r = 0; r < 4; r++) {
                int rg = bm + w * (TM / 4) + mf * 16 + lq * 4 + r;
                float v = acc[mf][nf][r] + bi;
                if (EPI == 1) {
                    v = fmaxf(v, 0.f);
                    Cb[(size_t)rg * Nn + cg] = __float2bfloat16(v);
                } else {
                    v += res[(size_t)rg * Nn + cg];
                    Cf[(size_t)rg * Nn + cg] = v;
                }
            }
        }
    }
}

// ---------------- QKV: bf16 MFMA GEMM + bias + RoPE + scatter --------------
// q pre-scaled by (1/sqrt(d))*log2(e) (attn uses exp2). v written TRANSPOSED
// vt[B,H,d,N] so attention can stage V tiles with zero-transpose async loads.
__global__ __launch_bounds__(256) void qkv_mfma(const __hip_bfloat16* __restrict__ A,
                                                const __hip_bfloat16* __restrict__ Wt,
                                                const float* __restrict__ bias,
                                                const float* __restrict__ fcos,
                                                const float* __restrict__ fsin,
                                                __hip_bfloat16* __restrict__ qout,
                                                __hip_bfloat16* __restrict__ kout,
                                                __hip_bfloat16* __restrict__ vt) {
    const int K = 256, Nn = 768;
    __shared__ __align__(16) __hip_bfloat16 As[128 * 32];
    __shared__ __align__(16) __hip_bfloat16 Bs[64 * 32];
    const int tid = threadIdx.x, w = tid >> 6, lane = tid & 63;
    const int lm = lane & 15, lq = lane >> 4;
    const int bm = blockIdx.y * 128, bn = blockIdx.x * 64;
    f32x4 acc[2][4];
    #pragma unroll
    for (int i = 0; i < 2; i++)
        #pragma unroll
        for (int j = 0; j < 4; j++) acc[i][j] = (f32x4){0.f, 0.f, 0.f, 0.f};

    const int sw = (lq ^ (lm & 3)) * 8;
    for (int k0 = 0; k0 < K; k0 += 32) {
        #pragma unroll
        for (int p = 0; p < 2; p++) {
            int c = p * 256 + tid;
            int r = c >> 2, gk = ((c & 3) ^ (r & 3)) * 8;
            gload16(A + (size_t)(bm + r) * K + k0 + gk, As + (p * 256 + w * 64) * 8);
        }
        {
            int r = tid >> 2, gk = ((tid & 3) ^ (r & 3)) * 8;
            gload16(Wt + (size_t)(bn + r) * K + k0 + gk, Bs + w * 512);
        }
        __syncthreads();
        short8 a0 = *(const short8*)&As[(w * 32 + lm) * 32 + sw];
        short8 a1 = *(const short8*)&As[(w * 32 + 16 + lm) * 32 + sw];
        #pragma unroll
        for (int nf = 0; nf < 4; nf++) {
            short8 bfr = *(const short8*)&Bs[(nf * 16 + lm) * 32 + sw];
            acc[0][nf] = __builtin_amdgcn_mfma_f32_16x16x32_bf16(a0, bfr, acc[0][nf], 0, 0, 0);
            acc[1][nf] = __builtin_amdgcn_mfma_f32_16x16x32_bf16(a1, bfr, acc[1][nf], 0, 0, 0);
        }
        __syncthreads();
    }
    const int seg = bn >> 8;  // 0=q 1=k 2=v, uniform per block
    #pragma unroll
    for (int nf = 0; nf < 4; nf++) {
        int cg = bn + nf * 16 + lm;
        int hh = (cg & 255) >> 5;
        int dd = (nf & 1) * 16 + lm;
        int i0 = dd >> 1;
        float bi = bias[cg];
        #pragma unroll
        for (int mf = 0; mf < 2; mf++) {
            #pragma unroll
            for (int r = 0; r < 4; r++) {
                int rg = bm + w * 32 + mf * 16 + lq * 4 + r;
                int bb = rg >> 11, n = rg & (Nseq - 1);
                float v = acc[mf][nf][r] + bi;
                if (seg == 2) {
                    vt[(((size_t)(bb * Hh + hh)) * Hd + dd) * Nseq + n] = __float2bfloat16(v);
                } else {
                    float vp = __shfl_xor(v, 1);
                    float cs = fcos[n * 16 + i0], sn = fsin[n * 16 + i0];
                    float outv = (dd & 1) ? (vp * sn + v * cs) : (v * cs - vp * sn);
                    if (seg == 0) outv *= QSC_;
                    __hip_bfloat16* dst = (seg == 0) ? qout : kout;
                    dst[(((size_t)(bb * Hh + hh)) * Nseq + n) * Hd + dd] = __float2bfloat16(outv);
                }
            }
        }
    }
}

// ---------------- Flash attention: 32x32 MFMA, key-split waves -------------
// Block = 64 q rows, 4 waves = 2 q-groups (wq) x 2 key-parities (wk).
// Wave (wq,wk) computes chunks kt=2t+wk for its 32 q rows: S^T = K·Q^T
// (reg-only P transpose via cndmask+shfl_xor(32)), P packed to bf16 with one
// v_perm (truncation). K/V staged per chunk-pair, double-buffered. Final
// cross-parity O/l reduction through LDS aliased onto the dead K buffer.
__global__ __launch_bounds__(256) void attn_mfma(const __hip_bfloat16* __restrict__ q,
                                                 const __hip_bfloat16* __restrict__ k,
                                                 const __hip_bfloat16* __restrict__ vt,
                                                 __hip_bfloat16* __restrict__ att) {
    __shared__ __align__(16) char smem[4096 + 16384 + 16384 + 512];
    __hip_bfloat16* Qs  = (__hip_bfloat16*)smem;               // 64x32
    __hip_bfloat16* KsB = (__hip_bfloat16*)(smem + 4096);      // [buf][par][32*64]
    __hip_bfloat16* VsB = (__hip_bfloat16*)(smem + 20480);     // [buf][par][32*64]
    float* RedO = (float*)(smem + 4096);                       // alias Ks (8 KB)
    float* RedS = (float*)(smem + 4096 + 8192);                // 2*32
    float* smS  = (float*)(smem + 4096 + 8192 + 256);          // 2*32

    const int tid = threadIdx.x, w = tid >> 6, lane = tid & 63;
    const int l31 = lane & 31, hi = lane >> 5;
    const int wq = w >> 1, wk = w & 1;
    const int bh = blockIdx.y, qbase = blockIdx.x * 64;
    const __hip_bfloat16* qp = q + ((size_t)bh * Nseq + qbase) * Hd;
    const __hip_bfloat16* kp = k + (size_t)bh * Nseq * Hd;
    const __hip_bfloat16* vp = vt + (size_t)bh * Hd * Nseq;
    const int r8 = tid >> 3, s8 = tid & 7;

    {   // Q: 64 rows x 32, 4-slot xor swizzle
        int r = tid >> 2, sl = tid & 3;
        gload16(qp + r * 32 + ((sl ^ (r & 3)) * 8), Qs + w * 512);
    }
    #pragma unroll
    for (int par = 0; par < 2; par++) {  // pair 0 (chunks 0,1) -> buf 0
        gload16(kp + (par * 64 + 2 * r8 + (s8 >> 2)) * 32 + (((s8 & 3) ^ (r8 & 3)) * 8),
                KsB + par * 2048 + w * 512);
        gload16(vp + (size_t)r8 * Nseq + par * 64 + ((s8 ^ (r8 & 7)) * 8),
                VsB + par * 2048 + w * 512);
    }
    __syncthreads();

    const int qrow = wq * 32 + l31;
    short8 qf0 = *(const short8*)&Qs[qrow * 32 + ((hi ^ (l31 & 3)) * 8)];
    short8 qf1 = *(const short8*)&Qs[qrow * 32 + (((2 + hi) ^ (l31 & 3)) * 8)];

    f32x16 O;
    #pragma unroll
    for (int i = 0; i < 16; i++) O[i] = 0.f;
    float sm = 0.f;

    for (int t = 0; t < 16; t++) {
        const int buf = t & 1;
        if (t + 1 < 16) {
            const int kb2 = (t + 1) * 128;
            #pragma unroll
            for (int par = 0; par < 2; par++) {
                gload16(kp + (kb2 + par * 64 + 2 * r8 + (s8 >> 2)) * 32 + (((s8 & 3) ^ (r8 & 3)) * 8),
                        KsB + ((buf ^ 1) * 2 + par) * 2048 + w * 512);
                gload16(vp + (size_t)r8 * Nseq + kb2 + par * 64 + ((s8 ^ (r8 & 7)) * 8),
                        VsB + ((buf ^ 1) * 2 + par) * 2048 + w * 512);
            }
        }
        const __hip_bfloat16* Kc = KsB + (buf * 2 + wk) * 2048;
        const __hip_bfloat16* Vc = VsB + (buf * 2 + wk) * 2048;
        // S^T[key][q]: keys 0-31 (St0) and 32-63 (St1) of this wave's chunk
        f32x16 St0, St1;
        #pragma unroll
        for (int i = 0; i < 16; i++) { St0[i] = 0.f; St1[i] = 0.f; }
        {
            int pr = l31 >> 1, elb = pr * 64 + (l31 & 1) * 32;
            short8 kf0 = *(const short8*)&Kc[elb + ((hi ^ (pr & 3)) * 8)];
            short8 kf1 = *(const short8*)&Kc[elb + (((2 + hi) ^ (pr & 3)) * 8)];
            St0 = __builtin_amdgcn_mfma_f32_32x32x16_bf16(kf0, qf0, St0, 0, 0, 0);
            St0 = __builtin_amdgcn_mfma_f32_32x32x16_bf16(kf1, qf1, St0, 0, 0, 0);
        }
        {
            int pr = 16 + (l31 >> 1), elb = pr * 64 + (l31 & 1) * 32;
            short8 kf0 = *(const short8*)&Kc[elb + ((hi ^ (pr & 3)) * 8)];
            short8 kf1 = *(const short8*)&Kc[elb + (((2 + hi) ^ (pr & 3)) * 8)];
            St1 = __builtin_amdgcn_mfma_f32_32x32x16_bf16(kf0, qf0, St1, 0, 0, 0);
            St1 = __builtin_amdgcn_mfma_f32_32x32x16_bf16(kf1, qf1, St1, 0, 0, 0);
        }
        // exp2 + single-instruction pair pack (regs 2p,2p+1 = consecutive keys)
        int pk0[8], pk1[8];
        #pragma unroll
        for (int p = 0; p < 8; p++) {
            float a = __builtin_amdgcn_exp2f(St0[2 * p]);
            float b = __builtin_amdgcn_exp2f(St0[2 * p + 1]);
            sm += a + b;
            pk0[p] = pk2bf(a, b);
        }
        #pragma unroll
        for (int p = 0; p < 8; p++) {
            float a = __builtin_amdgcn_exp2f(St1[2 * p]);
            float b = __builtin_amdgcn_exp2f(St1[2 * p + 1]);
            sm += a + b;
            pk1[p] = pk2bf(a, b);
        }
        // PV: per 16-key block tt, build P A-frag via reg-select + half-swap
        #pragma unroll
        for (int tt = 0; tt < 4; tt++) {
            const int* PK = (tt >> 1) ? pk1 : pk0;
            const int base = 4 * (tt & 1);
            int keep0 = hi ? PK[base + 2] : PK[base + 0];
            int keep1 = hi ? PK[base + 3] : PK[base + 1];
            int send0 = hi ? PK[base + 0] : PK[base + 2];
            int send1 = hi ? PK[base + 1] : PK[base + 3];
            int x0 = __shfl_xor(send0, 32);
            int x1 = __shfl_xor(send1, 32);
            I4S8 u;
            u.i[0] = hi ? x0 : keep0;
            u.i[1] = hi ? x1 : keep1;
            u.i[2] = hi ? keep0 : x0;
            u.i[3] = hi ? keep1 : x1;
            short8 vf = *(const short8*)&Vc[l31 * 64 + (((2 * tt + hi) ^ (l31 & 7)) * 8)];
            O = __builtin_amdgcn_mfma_f32_32x32x16_bf16(u.s, vf, O, 0, 0, 0);
        }
        __syncthreads();
    }
    // wave-local: both halves hold per-q sum over this wave's keys
    sm += __shfl_xor(sm, 32);
    // cross-parity reduction (Ks region is dead -> RedO/RedS alias it)
    if (wk == 1) {
        #pragma unroll
        for (int j = 0; j < 16; j++) RedO[(wq * 16 + j) * 64 + lane] = O[j];
        if (hi == 0) RedS[wq * 32 + l31] = sm;
    }
    __syncthreads();
    if (wk == 0) {
        #pragma unroll
        for (int j = 0; j < 16; j++) O[j] += RedO[(wq * 16 + j) * 64 + lane];
        sm += RedS[wq * 32 + l31];
        if (hi == 0) smS[wq * 32 + l31] = sm;
    }
    __syncthreads();
    if (wk == 0) {
        const int bb = bh >> 3, hh = bh & 7;
        #pragma unroll
        for (int m = 0; m < 4; m++) {
            float4 sv = *(const float4*)&smS[wq * 32 + 8 * m + 4 * hi];
            #pragma unroll
            for (int i = 0; i < 4; i++) {
                int n = qbase + wq * 32 + 8 * m + 4 * hi + i;
                att[((size_t)(bb * Nseq + n)) * Dm + hh * Hd + l31] =
                    __float2bfloat16(O[4 * m + i] * (1.0f / sv[i]));
            }
        }
    }
}

extern "C" void kernel_launch(void* const* d_in, const int* in_sizes, int n_in,
                              void* d_out, int out_size, void* d_ws, size_t ws_size,
                              hipStream_t stream) {
    const float* x      = (const float*)d_in[0];
    const float* fcos   = (const float*)d_in[1];
    const float* fsin   = (const float*)d_in[2];
    const float* w_qkv  = (const float*)d_in[3];
    const float* b_qkv  = (const float*)d_in[4];
    const float* w_proj = (const float*)d_in[5];
    const float* b_proj = (const float*)d_in[6];
    const float* ln1_g  = (const float*)d_in[7];
    const float* ln1_b  = (const float*)d_in[8];
    const float* ln2_g  = (const float*)d_in[9];
    const float* ln2_b  = (const float*)d_in[10];
    const float* w1     = (const float*)d_in[11];
    const float* b1     = (const float*)d_in[12];
    const float* w2     = (const float*)d_in[13];
    const float* b2     = (const float*)d_in[14];
    float* out = (float*)d_out;
    char* base = (char*)d_ws;
    const size_t MB = (size_t)1 << 20;

    __hip_bfloat16* h   = (__hip_bfloat16*)(base);            // 4 MB (dead after qkv)
    __hip_bfloat16* qb  = (__hip_bfloat16*)(base + 4 * MB);
    __hip_bfloat16* kbf = (__hip_bfloat16*)(base + 8 * MB);
    __hip_bfloat16* vtb = (__hip_bfloat16*)(base + 12 * MB);  // transposed [B,H,d,N]
    __hip_bfloat16* att = (__hip_bfloat16*)(base + 16 * MB);
    float*          x2f = (float*)(base + 20 * MB);           // 8 MB
    __hip_bfloat16* h2  = (__hip_bfloat16*)(base);            // reuse h slot
    __hip_bfloat16* ffn = (__hip_bfloat16*)(base + 28 * MB);  // 8 MB
    __hip_bfloat16* wqT = (__hip_bfloat16*)(base + 40 * MB);            // 768x256
    __hip_bfloat16* wpT = (__hip_bfloat16*)(base + 40 * MB + 393216);   // 256x256
    __hip_bfloat16* w1T = (__hip_bfloat16*)(base + 40 * MB + 524288);   // 512x256
    __hip_bfloat16* w2T = (__hip_bfloat16*)(base + 40 * MB + 786432);   // 256x512

    const int rows = Bsz * Nseq;  // 8192

    wconv_kernel<<<512, 256, 0, stream>>>(w_qkv, w_proj, w1, w2, wqT, wpT, w1T, w2T);
    ln_kernel<<<rows / 4, 256, 0, stream>>>(x, ln1_g, ln1_b, h);
    qkv_mfma<<<dim3(12, 64), 256, 0, stream>>>(h, wqT, b_qkv, fcos, fsin, qb, kbf, vtb);
    attn_mfma<<<dim3(Nseq / 64, Bsz * Hh), 256, 0, stream>>>(qb, kbf, vtb, att);
    mfma_gemm<64, 2><<<dim3(4, 128), 256, 0, stream>>>(att, wpT, b_proj, x, x2f, nullptr,
                                                       rows, 256, 256);
    ln_kernel<<<rows / 4, 256, 0, stream>>>(x2f, ln2_g, ln2_b, h2);
    mfma_gemm<128, 1><<<dim3(8, 64), 256, 0, stream>>>(h2, w1T, b1, nullptr, nullptr, ffn,
                                                       rows, 512, 256);
    mfma_gemm<64, 2><<<dim3(4, 128), 256, 0, stream>>>(ffn, w2T, b2, x2f, out, nullptr,
                                                       rows, 256, 512);
}

// Round 7
// 174.227 us; speedup vs baseline: 1.3219x; 1.0588x over previous
//
#include <hip/hip_runtime.h>
#include <hip/hip_bf16.h>
#include <math.h>

#define Bsz 4
#define Nseq 2048
#define Dm 256
#define Hh 8
#define Hd 32
#define EPS_ 1e-5f
#define SCALE_ 0.17677669529663687f               // 1/sqrt(32)
#define QSC_ (0.17677669529663687f * 1.4426950408889634f)  // fold log2(e) for exp2

typedef __attribute__((ext_vector_type(8))) short short8;
typedef __attribute__((ext_vector_type(4))) short short4v;
typedef __attribute__((ext_vector_type(4))) float f32x4;
typedef __attribute__((ext_vector_type(16))) float f32x16;

// async global->LDS, 16B per lane. LDS dest = wave-uniform base + lane*16.
__device__ __forceinline__ void gload16(const void* g, void* l) {
    __builtin_amdgcn_global_load_lds(
        (const __attribute__((address_space(1))) void*)g,
        (__attribute__((address_space(3))) void*)l, 16, 0, 0);
}

__device__ __forceinline__ short bf16s(float f) {
    __hip_bfloat16 h = __float2bfloat16(f);
    return *(short*)&h;
}

union FU { float f; unsigned u; };

// pack two fp32 -> (bf16(a) | bf16(b)<<16) via single v_perm_b32 (truncation)
__device__ __forceinline__ int pk2bf(float a, float b) {
    FU ua, ub; ua.f = a; ub.f = b;
    return (int)__builtin_amdgcn_perm(ub.u, ua.u, 0x07060302u);
}

union I4S8 { int i[4]; short8 s; };

// ---------------- prep: LN1 (bid<2048) + weight transpose (bid>=2048) ------
__global__ __launch_bounds__(256) void prep_kernel(
    const float* __restrict__ x, const float* __restrict__ g1,
    const float* __restrict__ b1v, __hip_bfloat16* __restrict__ hout,
    const float* __restrict__ s0, const float* __restrict__ s1,
    const float* __restrict__ s2, const float* __restrict__ s3,
    __hip_bfloat16* __restrict__ d0, __hip_bfloat16* __restrict__ d1,
    __hip_bfloat16* __restrict__ d2, __hip_bfloat16* __restrict__ d3) {
    __shared__ float t[32][33];
    if (blockIdx.x < 2048) {
        int row  = blockIdx.x * 4 + (threadIdx.x >> 6);
        int lane = threadIdx.x & 63;
        const float* xr = x + (size_t)row * Dm;
        float4 v = *(const float4*)(xr + lane * 4);
        float s  = v.x + v.y + v.z + v.w;
        float ss = v.x * v.x + v.y * v.y + v.z * v.z + v.w * v.w;
        #pragma unroll
        for (int off = 32; off; off >>= 1) {
            s  += __shfl_xor(s, off);
            ss += __shfl_xor(ss, off);
        }
        float mu  = s * (1.0f / Dm);
        float var = ss * (1.0f / Dm) - mu * mu;
        float rs  = rsqrtf(var + EPS_);
        float4 gv = *(const float4*)(g1 + lane * 4);
        float4 bv = *(const float4*)(b1v + lane * 4);
        short4v o4 = { bf16s((v.x - mu) * rs * gv.x + bv.x),
                       bf16s((v.y - mu) * rs * gv.y + bv.y),
                       bf16s((v.z - mu) * rs * gv.z + bv.z),
                       bf16s((v.w - mu) * rs * gv.w + bv.w) };
        *(short4v*)(hout + (size_t)row * Dm + lane * 4) = o4;
        return;
    }
    int bid = blockIdx.x - 2048;
    const float* src; __hip_bfloat16* dst; int K, N, tb;
    if (bid < 192)      { src = s0; dst = d0; K = 256; N = 768; tb = bid; }
    else if (bid < 256) { src = s1; dst = d1; K = 256; N = 256; tb = bid - 192; }
    else if (bid < 384) { src = s2; dst = d2; K = 256; N = 512; tb = bid - 256; }
    else                { src = s3; dst = d3; K = 512; N = 256; tb = bid - 384; }
    int tn = N >> 5;
    int k0 = (tb / tn) * 32, n0 = (tb % tn) * 32;
    int c = threadIdx.x & 31, r0 = threadIdx.x >> 5;
    #pragma unroll
    for (int i = 0; i < 4; i++) {
        int r = r0 + i * 8;
        t[r][c] = src[(size_t)(k0 + r) * N + n0 + c];
    }
    __syncthreads();
    #pragma unroll
    for (int i = 0; i < 4; i++) {
        int n = r0 + i * 8;
        dst[(size_t)(n0 + n) * K + k0 + c] = __float2bfloat16(t[c][n]);
    }
}

// ---------------- LayerNorm (for ln2): one wave per row, bf16 output -------
__global__ __launch_bounds__(256) void ln_kernel(const float* __restrict__ x,
                                                 const float* __restrict__ g,
                                                 const float* __restrict__ b,
                                                 __hip_bfloat16* __restrict__ out) {
    int row  = blockIdx.x * 4 + (threadIdx.x >> 6);
    int lane = threadIdx.x & 63;
    const float* xr = x + (size_t)row * Dm;
    float4 v = *(const float4*)(xr + lane * 4);
    float s  = v.x + v.y + v.z + v.w;
    float ss = v.x * v.x + v.y * v.y + v.z * v.z + v.w * v.w;
    #pragma unroll
    for (int off = 32; off; off >>= 1) {
        s  += __shfl_xor(s, off);
        ss += __shfl_xor(ss, off);
    }
    float mu  = s * (1.0f / Dm);
    float var = ss * (1.0f / Dm) - mu * mu;
    float rs  = rsqrtf(var + EPS_);
    float4 gv = *(const float4*)(g + lane * 4);
    float4 bv = *(const float4*)(b + lane * 4);
    short4v o4 = { bf16s((v.x - mu) * rs * gv.x + bv.x),
                   bf16s((v.y - mu) * rs * gv.y + bv.y),
                   bf16s((v.z - mu) * rs * gv.z + bv.z),
                   bf16s((v.w - mu) * rs * gv.w + bv.w) };
    *(short4v*)(out + (size_t)row * Dm + lane * 4) = o4;
}

// ---------------- bf16 MFMA GEMM, BK=64, LDS dbuf, 1 barrier/iter ----------
// Tile 64x64. 8-slot xor swizzle: row r slot s holds k-chunk s^(r&7); frag
// b128 reads tile all 32 banks 2-way (free). Prefetch for buf^1 issued right
// after the barrier that opens compute on buf -> overlaps whole compute phase.
// EPI 1: relu -> bf16 out. EPI 2: + res(fp32) -> fp32 out.
template <int EPI>
__global__ __launch_bounds__(256) void mfma_gemm(const __hip_bfloat16* __restrict__ A,
                                                 const __hip_bfloat16* __restrict__ Wt,
                                                 const float* __restrict__ bias,
                                                 const float* __restrict__ res,
                                                 float* __restrict__ Cf,
                                                 __hip_bfloat16* __restrict__ Cb,
                                                 int M, int Nn, int K) {
    __shared__ __align__(16) __hip_bfloat16 As[2][64 * 64];
    __shared__ __align__(16) __hip_bfloat16 Bs[2][64 * 64];
    const int tid = threadIdx.x, w = tid >> 6, lane = tid & 63;
    const int lm = lane & 15, lq = lane >> 4;
    const int bm = blockIdx.y * 64, bn = blockIdx.x * 64;
    f32x4 acc[4];
    #pragma unroll
    for (int j = 0; j < 4; j++) acc[j] = (f32x4){0.f, 0.f, 0.f, 0.f};

    const int sr = tid >> 3, ssl = tid & 7;           // staging row/slot
    const int sgk = (ssl ^ (sr & 7)) * 8;
    const int sr2 = 32 + sr;                          // second round row
    const int sgk2 = (ssl ^ (sr2 & 7)) * 8;

    // stage buf0, k0=0
    gload16(A + (size_t)(bm + sr) * K + sgk, &As[0][w * 512]);
    gload16(A + (size_t)(bm + sr2) * K + sgk2, &As[0][2048 + w * 512]);
    gload16(Wt + (size_t)(bn + sr) * K + sgk, &Bs[0][w * 512]);
    gload16(Wt + (size_t)(bn + sr2) * K + sgk2, &Bs[0][2048 + w * 512]);

    const int arow = w * 16 + lm;
    const int ar7 = arow & 7, cr7base = lm & 7;
    for (int t = 0; t < K / 64; t++) {
        const int buf = t & 1;
        __syncthreads();   // buf ready (vmcnt drain); prev-iter reads done
        if (t + 1 < K / 64) {
            int k0 = (t + 1) * 64;
            gload16(A + (size_t)(bm + sr) * K + k0 + sgk, &As[buf ^ 1][w * 512]);
            gload16(A + (size_t)(bm + sr2) * K + k0 + sgk2, &As[buf ^ 1][2048 + w * 512]);
            gload16(Wt + (size_t)(bn + sr) * K + k0 + sgk, &Bs[buf ^ 1][w * 512]);
            gload16(Wt + (size_t)(bn + sr2) * K + k0 + sgk2, &Bs[buf ^ 1][2048 + w * 512]);
        }
        #pragma unroll
        for (int ks = 0; ks < 2; ks++) {
            short8 a = *(const short8*)&As[buf][arow * 64 + (((ks * 4 + lq) ^ ar7) * 8)];
            #pragma unroll
            for (int nf = 0; nf < 4; nf++) {
                int cc = nf * 16 + lm;
                short8 bfr = *(const short8*)&Bs[buf][cc * 64 + (((ks * 4 + lq) ^ (cc & 7)) * 8)];
                acc[nf] = __builtin_amdgcn_mfma_f32_16x16x32_bf16(a, bfr, acc[nf], 0, 0, 0);
            }
        }
    }
    #pragma unroll
    for (int nf = 0; nf < 4; nf++) {
        int cg = bn + nf * 16 + lm;
        float bi = bias[cg];
        #pragma unroll
        for (int r = 0; r < 4; r++) {
            int rg = bm + w * 16 + lq * 4 + r;
            float v = acc[nf][r] + bi;
            if (EPI == 1) {
                v = fmaxf(v, 0.f);
                Cb[(size_t)rg * Nn + cg] = __float2bfloat16(v);
            } else {
                v += res[(size_t)rg * Nn + cg];
                Cf[(size_t)rg * Nn + cg] = v;
            }
        }
    }
}

// ---------------- QKV: same BK=64 dbuf core + bias/RoPE/scatter epilogue ---
// q pre-scaled by (1/sqrt(d))*log2(e). v written TRANSPOSED vt[B,H,d,N].
__global__ __launch_bounds__(256) void qkv_mfma(const __hip_bfloat16* __restrict__ A,
                                                const __hip_bfloat16* __restrict__ Wt,
                                                const float* __restrict__ bias,
                                                const float* __restrict__ fcos,
                                                const float* __restrict__ fsin,
                                                __hip_bfloat16* __restrict__ qout,
                                                __hip_bfloat16* __restrict__ kout,
                                                __hip_bfloat16* __restrict__ vt) {
    const int K = 256;
    __shared__ __align__(16) __hip_bfloat16 As[2][64 * 64];
    __shared__ __align__(16) __hip_bfloat16 Bs[2][64 * 64];
    const int tid = threadIdx.x, w = tid >> 6, lane = tid & 63;
    const int lm = lane & 15, lq = lane >> 4;
    const int bm = blockIdx.y * 64, bn = blockIdx.x * 64;
    f32x4 acc[4];
    #pragma unroll
    for (int j = 0; j < 4; j++) acc[j] = (f32x4){0.f, 0.f, 0.f, 0.f};

    const int sr = tid >> 3, ssl = tid & 7;
    const int sgk = (ssl ^ (sr & 7)) * 8;
    const int sr2 = 32 + sr;
    const int sgk2 = (ssl ^ (sr2 & 7)) * 8;

    gload16(A + (size_t)(bm + sr) * K + sgk, &As[0][w * 512]);
    gload16(A + (size_t)(bm + sr2) * K + sgk2, &As[0][2048 + w * 512]);
    gload16(Wt + (size_t)(bn + sr) * K + sgk, &Bs[0][w * 512]);
    gload16(Wt + (size_t)(bn + sr2) * K + sgk2, &Bs[0][2048 + w * 512]);

    const int arow = w * 16 + lm;
    const int ar7 = arow & 7;
    for (int t = 0; t < K / 64; t++) {
        const int buf = t & 1;
        __syncthreads();
        if (t + 1 < K / 64) {
            int k0 = (t + 1) * 64;
            gload16(A + (size_t)(bm + sr) * K + k0 + sgk, &As[buf ^ 1][w * 512]);
            gload16(A + (size_t)(bm + sr2) * K + k0 + sgk2, &As[buf ^ 1][2048 + w * 512]);
            gload16(Wt + (size_t)(bn + sr) * K + k0 + sgk, &Bs[buf ^ 1][w * 512]);
            gload16(Wt + (size_t)(bn + sr2) * K + k0 + sgk2, &Bs[buf ^ 1][2048 + w * 512]);
        }
        #pragma unroll
        for (int ks = 0; ks < 2; ks++) {
            short8 a = *(const short8*)&As[buf][arow * 64 + (((ks * 4 + lq) ^ ar7) * 8)];
            #pragma unroll
            for (int nf = 0; nf < 4; nf++) {
                int cc = nf * 16 + lm;
                short8 bfr = *(const short8*)&Bs[buf][cc * 64 + (((ks * 4 + lq) ^ (cc & 7)) * 8)];
                acc[nf] = __builtin_amdgcn_mfma_f32_16x16x32_bf16(a, bfr, acc[nf], 0, 0, 0);
            }
        }
    }
    const int seg = bn >> 8;  // 0=q 1=k 2=v, uniform per block
    #pragma unroll
    for (int nf = 0; nf < 4; nf++) {
        int cg = bn + nf * 16 + lm;
        int hh = (cg & 255) >> 5;
        int dd = (nf & 1) * 16 + lm;
        int i0 = dd >> 1;
        float bi = bias[cg];
        #pragma unroll
        for (int r = 0; r < 4; r++) {
            int rg = bm + w * 16 + lq * 4 + r;
            int bb = rg >> 11, n = rg & (Nseq - 1);
            float v = acc[nf][r] + bi;
            if (seg == 2) {
                vt[(((size_t)(bb * Hh + hh)) * Hd + dd) * Nseq + n] = __float2bfloat16(v);
            } else {
                float vp = __shfl_xor(v, 1);
                float cs = fcos[n * 16 + i0], sn = fsin[n * 16 + i0];
                float outv = (dd & 1) ? (vp * sn + v * cs) : (v * cs - vp * sn);
                if (seg == 0) outv *= QSC_;
                __hip_bfloat16* dst = (seg == 0) ? qout : kout;
                dst[(((size_t)(bb * Hh + hh)) * Nseq + n) * Hd + dd] = __float2bfloat16(outv);
            }
        }
    }
}

// ---------------- Flash attention: 32x32 MFMA, key-split waves -------------
// (unchanged from round 6)
__global__ __launch_bounds__(256) void attn_mfma(const __hip_bfloat16* __restrict__ q,
                                                 const __hip_bfloat16* __restrict__ k,
                                                 const __hip_bfloat16* __restrict__ vt,
                                                 __hip_bfloat16* __restrict__ att) {
    __shared__ __align__(16) char smem[4096 + 16384 + 16384 + 512];
    __hip_bfloat16* Qs  = (__hip_bfloat16*)smem;               // 64x32
    __hip_bfloat16* KsB = (__hip_bfloat16*)(smem + 4096);      // [buf][par][32*64]
    __hip_bfloat16* VsB = (__hip_bfloat16*)(smem + 20480);     // [buf][par][32*64]
    float* RedO = (float*)(smem + 4096);                       // alias Ks (8 KB)
    float* RedS = (float*)(smem + 4096 + 8192);                // 2*32
    float* smS  = (float*)(smem + 4096 + 8192 + 256);          // 2*32

    const int tid = threadIdx.x, w = tid >> 6, lane = tid & 63;
    const int l31 = lane & 31, hi = lane >> 5;
    const int wq = w >> 1, wk = w & 1;
    const int bh = blockIdx.y, qbase = blockIdx.x * 64;
    const __hip_bfloat16* qp = q + ((size_t)bh * Nseq + qbase) * Hd;
    const __hip_bfloat16* kp = k + (size_t)bh * Nseq * Hd;
    const __hip_bfloat16* vp = vt + (size_t)bh * Hd * Nseq;
    const int r8 = tid >> 3, s8 = tid & 7;

    {   // Q: 64 rows x 32, 4-slot xor swizzle
        int r = tid >> 2, sl = tid & 3;
        gload16(qp + r * 32 + ((sl ^ (r & 3)) * 8), Qs + w * 512);
    }
    #pragma unroll
    for (int par = 0; par < 2; par++) {  // pair 0 (chunks 0,1) -> buf 0
        gload16(kp + (par * 64 + 2 * r8 + (s8 >> 2)) * 32 + (((s8 & 3) ^ (r8 & 3)) * 8),
                KsB + par * 2048 + w * 512);
        gload16(vp + (size_t)r8 * Nseq + par * 64 + ((s8 ^ (r8 & 7)) * 8),
                VsB + par * 2048 + w * 512);
    }
    __syncthreads();

    const int qrow = wq * 32 + l31;
    short8 qf0 = *(const short8*)&Qs[qrow * 32 + ((hi ^ (l31 & 3)) * 8)];
    short8 qf1 = *(const short8*)&Qs[qrow * 32 + (((2 + hi) ^ (l31 & 3)) * 8)];

    f32x16 O;
    #pragma unroll
    for (int i = 0; i < 16; i++) O[i] = 0.f;
    float sm = 0.f;

    for (int t = 0; t < 16; t++) {
        const int buf = t & 1;
        if (t + 1 < 16) {
            const int kb2 = (t + 1) * 128;
            #pragma unroll
            for (int par = 0; par < 2; par++) {
                gload16(kp + (kb2 + par * 64 + 2 * r8 + (s8 >> 2)) * 32 + (((s8 & 3) ^ (r8 & 3)) * 8),
                        KsB + ((buf ^ 1) * 2 + par) * 2048 + w * 512);
                gload16(vp + (size_t)r8 * Nseq + kb2 + par * 64 + ((s8 ^ (r8 & 7)) * 8),
                        VsB + ((buf ^ 1) * 2 + par) * 2048 + w * 512);
            }
        }
        const __hip_bfloat16* Kc = KsB + (buf * 2 + wk) * 2048;
        const __hip_bfloat16* Vc = VsB + (buf * 2 + wk) * 2048;
        f32x16 St0, St1;
        #pragma unroll
        for (int i = 0; i < 16; i++) { St0[i] = 0.f; St1[i] = 0.f; }
        {
            int pr = l31 >> 1, elb = pr * 64 + (l31 & 1) * 32;
            short8 kf0 = *(const short8*)&Kc[elb + ((hi ^ (pr & 3)) * 8)];
            short8 kf1 = *(const short8*)&Kc[elb + (((2 + hi) ^ (pr & 3)) * 8)];
            St0 = __builtin_amdgcn_mfma_f32_32x32x16_bf16(kf0, qf0, St0, 0, 0, 0);
            St0 = __builtin_amdgcn_mfma_f32_32x32x16_bf16(kf1, qf1, St0, 0, 0, 0);
        }
        {
            int pr = 16 + (l31 >> 1), elb = pr * 64 + (l31 & 1) * 32;
            short8 kf0 = *(const short8*)&Kc[elb + ((hi ^ (pr & 3)) * 8)];
            short8 kf1 = *(const short8*)&Kc[elb + (((2 + hi) ^ (pr & 3)) * 8)];
            St1 = __builtin_amdgcn_mfma_f32_32x32x16_bf16(kf0, qf0, St1, 0, 0, 0);
            St1 = __builtin_amdgcn_mfma_f32_32x32x16_bf16(kf1, qf1, St1, 0, 0, 0);
        }
        int pk0[8], pk1[8];
        #pragma unroll
        for (int p = 0; p < 8; p++) {
            float a = __builtin_amdgcn_exp2f(St0[2 * p]);
            float b = __builtin_amdgcn_exp2f(St0[2 * p + 1]);
            sm += a + b;
            pk0[p] = pk2bf(a, b);
        }
        #pragma unroll
        for (int p = 0; p < 8; p++) {
            float a = __builtin_amdgcn_exp2f(St1[2 * p]);
            float b = __builtin_amdgcn_exp2f(St1[2 * p + 1]);
            sm += a + b;
            pk1[p] = pk2bf(a, b);
        }
        #pragma unroll
        for (int tt = 0; tt < 4; tt++) {
            const int* PK = (tt >> 1) ? pk1 : pk0;
            const int base = 4 * (tt & 1);
            int keep0 = hi ? PK[base + 2] : PK[base + 0];
            int keep1 = hi ? PK[base + 3] : PK[base + 1];
            int send0 = hi ? PK[base + 0] : PK[base + 2];
            int send1 = hi ? PK[base + 1] : PK[base + 3];
            int x0 = __shfl_xor(send0, 32);
            int x1 = __shfl_xor(send1, 32);
            I4S8 u;
            u.i[0] = hi ? x0 : keep0;
            u.i[1] = hi ? x1 : keep1;
            u.i[2] = hi ? keep0 : x0;
            u.i[3] = hi ? keep1 : x1;
            short8 vf = *(const short8*)&Vc[l31 * 64 + (((2 * tt + hi) ^ (l31 & 7)) * 8)];
            O = __builtin_amdgcn_mfma_f32_32x32x16_bf16(u.s, vf, O, 0, 0, 0);
        }
        __syncthreads();
    }
    sm += __shfl_xor(sm, 32);
    if (wk == 1) {
        #pragma unroll
        for (int j = 0; j < 16; j++) RedO[(wq * 16 + j) * 64 + lane] = O[j];
        if (hi == 0) RedS[wq * 32 + l31] = sm;
    }
    __syncthreads();
    if (wk == 0) {
        #pragma unroll
        for (int j = 0; j < 16; j++) O[j] += RedO[(wq * 16 + j) * 64 + lane];
        sm += RedS[wq * 32 + l31];
        if (hi == 0) smS[wq * 32 + l31] = sm;
    }
    __syncthreads();
    if (wk == 0) {
        const int bb = bh >> 3, hh = bh & 7;
        #pragma unroll
        for (int m = 0; m < 4; m++) {
            float4 sv = *(const float4*)&smS[wq * 32 + 8 * m + 4 * hi];
            #pragma unroll
            for (int i = 0; i < 4; i++) {
                int n = qbase + wq * 32 + 8 * m + 4 * hi + i;
                att[((size_t)(bb * Nseq + n)) * Dm + hh * Hd + l31] =
                    __float2bfloat16(O[4 * m + i] * (1.0f / sv[i]));
            }
        }
    }
}

extern "C" void kernel_launch(void* const* d_in, const int* in_sizes, int n_in,
                              void* d_out, int out_size, void* d_ws, size_t ws_size,
                              hipStream_t stream) {
    const float* x      = (const float*)d_in[0];
    const float* fcos   = (const float*)d_in[1];
    const float* fsin   = (const float*)d_in[2];
    const float* w_qkv  = (const float*)d_in[3];
    const float* b_qkv  = (const float*)d_in[4];
    const float* w_proj = (const float*)d_in[5];
    const float* b_proj = (const float*)d_in[6];
    const float* ln1_g  = (const float*)d_in[7];
    const float* ln1_b  = (const float*)d_in[8];
    const float* ln2_g  = (const float*)d_in[9];
    const float* ln2_b  = (const float*)d_in[10];
    const float* w1     = (const float*)d_in[11];
    const float* b1     = (const float*)d_in[12];
    const float* w2     = (const float*)d_in[13];
    const float* b2     = (const float*)d_in[14];
    float* out = (float*)d_out;
    char* base = (char*)d_ws;
    const size_t MB = (size_t)1 << 20;

    __hip_bfloat16* h   = (__hip_bfloat16*)(base);            // 4 MB (dead after qkv)
    __hip_bfloat16* qb  = (__hip_bfloat16*)(base + 4 * MB);
    __hip_bfloat16* kbf = (__hip_bfloat16*)(base + 8 * MB);
    __hip_bfloat16* vtb = (__hip_bfloat16*)(base + 12 * MB);  // transposed [B,H,d,N]
    __hip_bfloat16* att = (__hip_bfloat16*)(base + 16 * MB);
    float*          x2f = (float*)(base + 20 * MB);           // 8 MB
    __hip_bfloat16* h2  = (__hip_bfloat16*)(base);            // reuse h slot
    __hip_bfloat16* ffn = (__hip_bfloat16*)(base + 28 * MB);  // 8 MB
    __hip_bfloat16* wqT = (__hip_bfloat16*)(base + 40 * MB);            // 768x256
    __hip_bfloat16* wpT = (__hip_bfloat16*)(base + 40 * MB + 393216);   // 256x256
    __hip_bfloat16* w1T = (__hip_bfloat16*)(base + 40 * MB + 524288);   // 512x256
    __hip_bfloat16* w2T = (__hip_bfloat16*)(base + 40 * MB + 786432);   // 256x512

    const int rows = Bsz * Nseq;  // 8192

    prep_kernel<<<2560, 256, 0, stream>>>(x, ln1_g, ln1_b, h,
                                          w_qkv, w_proj, w1, w2, wqT, wpT, w1T, w2T);
    qkv_mfma<<<dim3(12, 128), 256, 0, stream>>>(h, wqT, b_qkv, fcos, fsin, qb, kbf, vtb);
    attn_mfma<<<dim3(Nseq / 64, Bsz * Hh), 256, 0, stream>>>(qb, kbf, vtb, att);
    mfma_gemm<2><<<dim3(4, 128), 256, 0, stream>>>(att, wpT, b_proj, x, x2f, nullptr,
                                                   rows, 256, 256);
    ln_kernel<<<rows / 4, 256, 0, stream>>>(x2f, ln2_g, ln2_b, h2);
    mfma_gemm<1><<<dim3(8, 128), 256, 0, stream>>>(h2, w1T, b1, nullptr, nullptr, ffn,
                                                   rows, 512, 256);
    mfma_gemm<2><<<dim3(4, 128), 256, 0, stream>>>(ffn, w2T, b2, x2f, out, nullptr,
                                                   rows, 256, 512);
}

// Round 8
// 172.515 us; speedup vs baseline: 1.3351x; 1.0099x over previous
//
#include <hip/hip_runtime.h>
#include <hip/hip_bf16.h>
#include <math.h>

#define Bsz 4
#define Nseq 2048
#define Dm 256
#define Hh 8
#define Hd 32
#define EPS_ 1e-5f
#define SCALE_ 0.17677669529663687f               // 1/sqrt(32)
#define QSC_ (0.17677669529663687f * 1.4426950408889634f)  // fold log2(e) for exp2

typedef __attribute__((ext_vector_type(8))) short short8;
typedef __attribute__((ext_vector_type(4))) short short4v;
typedef __attribute__((ext_vector_type(4))) float f32x4;
typedef __attribute__((ext_vector_type(16))) float f32x16;

// async global->LDS, 16B per lane. LDS dest = wave-uniform base + lane*16.
__device__ __forceinline__ void gload16(const void* g, void* l) {
    __builtin_amdgcn_global_load_lds(
        (const __attribute__((address_space(1))) void*)g,
        (__attribute__((address_space(3))) void*)l, 16, 0, 0);
}

__device__ __forceinline__ short bf16s(float f) {
    __hip_bfloat16 h = __float2bfloat16(f);
    return *(short*)&h;
}

union FU { float f; unsigned u; };

// pack two fp32 -> (bf16(a) | bf16(b)<<16) via single v_perm_b32 (truncation)
__device__ __forceinline__ int pk2bf(float a, float b) {
    FU ua, ub; ua.f = a; ub.f = b;
    return (int)__builtin_amdgcn_perm(ub.u, ua.u, 0x07060302u);
}

union I4S8 { int i[4]; short8 s; };

// ---------------- prep: LN1 (bid<2048) + weight transpose (bid>=2048) ------
__global__ __launch_bounds__(256) void prep_kernel(
    const float* __restrict__ x, const float* __restrict__ g1,
    const float* __restrict__ b1v, __hip_bfloat16* __restrict__ hout,
    const float* __restrict__ s0, const float* __restrict__ s1,
    const float* __restrict__ s2, const float* __restrict__ s3,
    __hip_bfloat16* __restrict__ d0, __hip_bfloat16* __restrict__ d1,
    __hip_bfloat16* __restrict__ d2, __hip_bfloat16* __restrict__ d3) {
    __shared__ float t[32][33];
    if (blockIdx.x < 2048) {
        int row  = blockIdx.x * 4 + (threadIdx.x >> 6);
        int lane = threadIdx.x & 63;
        const float* xr = x + (size_t)row * Dm;
        float4 v = *(const float4*)(xr + lane * 4);
        float s  = v.x + v.y + v.z + v.w;
        float ss = v.x * v.x + v.y * v.y + v.z * v.z + v.w * v.w;
        #pragma unroll
        for (int off = 32; off; off >>= 1) {
            s  += __shfl_xor(s, off);
            ss += __shfl_xor(ss, off);
        }
        float mu  = s * (1.0f / Dm);
        float var = ss * (1.0f / Dm) - mu * mu;
        float rs  = rsqrtf(var + EPS_);
        float4 gv = *(const float4*)(g1 + lane * 4);
        float4 bv = *(const float4*)(b1v + lane * 4);
        short4v o4 = { bf16s((v.x - mu) * rs * gv.x + bv.x),
                       bf16s((v.y - mu) * rs * gv.y + bv.y),
                       bf16s((v.z - mu) * rs * gv.z + bv.z),
                       bf16s((v.w - mu) * rs * gv.w + bv.w) };
        *(short4v*)(hout + (size_t)row * Dm + lane * 4) = o4;
        return;
    }
    int bid = blockIdx.x - 2048;
    const float* src; __hip_bfloat16* dst; int K, N, tb;
    if (bid < 192)      { src = s0; dst = d0; K = 256; N = 768; tb = bid; }
    else if (bid < 256) { src = s1; dst = d1; K = 256; N = 256; tb = bid - 192; }
    else if (bid < 384) { src = s2; dst = d2; K = 256; N = 512; tb = bid - 256; }
    else                { src = s3; dst = d3; K = 512; N = 256; tb = bid - 384; }
    int tn = N >> 5;
    int k0 = (tb / tn) * 32, n0 = (tb % tn) * 32;
    int c = threadIdx.x & 31, r0 = threadIdx.x >> 5;
    #pragma unroll
    for (int i = 0; i < 4; i++) {
        int r = r0 + i * 8;
        t[r][c] = src[(size_t)(k0 + r) * N + n0 + c];
    }
    __syncthreads();
    #pragma unroll
    for (int i = 0; i < 4; i++) {
        int n = r0 + i * 8;
        dst[(size_t)(n0 + n) * K + k0 + c] = __float2bfloat16(t[c][n]);
    }
}

// ---------------- QKV: BK=64 dbuf MFMA GEMM + bias/RoPE/scatter ------------
__global__ __launch_bounds__(256) void qkv_mfma(const __hip_bfloat16* __restrict__ A,
                                                const __hip_bfloat16* __restrict__ Wt,
                                                const float* __restrict__ bias,
                                                const float* __restrict__ fcos,
                                                const float* __restrict__ fsin,
                                                __hip_bfloat16* __restrict__ qout,
                                                __hip_bfloat16* __restrict__ kout,
                                                __hip_bfloat16* __restrict__ vt) {
    const int K = 256;
    __shared__ __align__(16) __hip_bfloat16 As[2][64 * 64];
    __shared__ __align__(16) __hip_bfloat16 Bs[2][64 * 64];
    const int tid = threadIdx.x, w = tid >> 6, lane = tid & 63;
    const int lm = lane & 15, lq = lane >> 4;
    const int bm = blockIdx.y * 64, bn = blockIdx.x * 64;
    f32x4 acc[4];
    #pragma unroll
    for (int j = 0; j < 4; j++) acc[j] = (f32x4){0.f, 0.f, 0.f, 0.f};

    const int sr = tid >> 3, ssl = tid & 7;
    const int sgk = (ssl ^ (sr & 7)) * 8;
    const int sr2 = 32 + sr;
    const int sgk2 = (ssl ^ (sr2 & 7)) * 8;

    gload16(A + (size_t)(bm + sr) * K + sgk, &As[0][w * 512]);
    gload16(A + (size_t)(bm + sr2) * K + sgk2, &As[0][2048 + w * 512]);
    gload16(Wt + (size_t)(bn + sr) * K + sgk, &Bs[0][w * 512]);
    gload16(Wt + (size_t)(bn + sr2) * K + sgk2, &Bs[0][2048 + w * 512]);

    const int arow = w * 16 + lm;
    const int ar7 = arow & 7;
    for (int t = 0; t < K / 64; t++) {
        const int buf = t & 1;
        __syncthreads();
        if (t + 1 < K / 64) {
            int k0 = (t + 1) * 64;
            gload16(A + (size_t)(bm + sr) * K + k0 + sgk, &As[buf ^ 1][w * 512]);
            gload16(A + (size_t)(bm + sr2) * K + k0 + sgk2, &As[buf ^ 1][2048 + w * 512]);
            gload16(Wt + (size_t)(bn + sr) * K + k0 + sgk, &Bs[buf ^ 1][w * 512]);
            gload16(Wt + (size_t)(bn + sr2) * K + k0 + sgk2, &Bs[buf ^ 1][2048 + w * 512]);
        }
        #pragma unroll
        for (int ks = 0; ks < 2; ks++) {
            short8 a = *(const short8*)&As[buf][arow * 64 + (((ks * 4 + lq) ^ ar7) * 8)];
            #pragma unroll
            for (int nf = 0; nf < 4; nf++) {
                int cc = nf * 16 + lm;
                short8 bfr = *(const short8*)&Bs[buf][cc * 64 + (((ks * 4 + lq) ^ (cc & 7)) * 8)];
                acc[nf] = __builtin_amdgcn_mfma_f32_16x16x32_bf16(a, bfr, acc[nf], 0, 0, 0);
            }
        }
    }
    const int seg = bn >> 8;  // 0=q 1=k 2=v, uniform per block
    #pragma unroll
    for (int nf = 0; nf < 4; nf++) {
        int cg = bn + nf * 16 + lm;
        int hh = (cg & 255) >> 5;
        int dd = (nf & 1) * 16 + lm;
        int i0 = dd >> 1;
        float bi = bias[cg];
        #pragma unroll
        for (int r = 0; r < 4; r++) {
            int rg = bm + w * 16 + lq * 4 + r;
            int bb = rg >> 11, n = rg & (Nseq - 1);
            float v = acc[nf][r] + bi;
            if (seg == 2) {
                vt[(((size_t)(bb * Hh + hh)) * Hd + dd) * Nseq + n] = __float2bfloat16(v);
            } else {
                float vp = __shfl_xor(v, 1);
                float cs = fcos[n * 16 + i0], sn = fsin[n * 16 + i0];
                float outv = (dd & 1) ? (vp * sn + v * cs) : (v * cs - vp * sn);
                if (seg == 0) outv *= QSC_;
                __hip_bfloat16* dst = (seg == 0) ? qout : kout;
                dst[(((size_t)(bb * Hh + hh)) * Nseq + n) * Hd + dd] = __float2bfloat16(outv);
            }
        }
    }
}

// ---------------- Flash attention: 32x32 MFMA, key-split waves -------------
// (unchanged from round 6/7)
__global__ __launch_bounds__(256) void attn_mfma(const __hip_bfloat16* __restrict__ q,
                                                 const __hip_bfloat16* __restrict__ k,
                                                 const __hip_bfloat16* __restrict__ vt,
                                                 __hip_bfloat16* __restrict__ att) {
    __shared__ __align__(16) char smem[4096 + 16384 + 16384 + 512];
    __hip_bfloat16* Qs  = (__hip_bfloat16*)smem;               // 64x32
    __hip_bfloat16* KsB = (__hip_bfloat16*)(smem + 4096);      // [buf][par][32*64]
    __hip_bfloat16* VsB = (__hip_bfloat16*)(smem + 20480);     // [buf][par][32*64]
    float* RedO = (float*)(smem + 4096);                       // alias Ks (8 KB)
    float* RedS = (float*)(smem + 4096 + 8192);                // 2*32
    float* smS  = (float*)(smem + 4096 + 8192 + 256);          // 2*32

    const int tid = threadIdx.x, w = tid >> 6, lane = tid & 63;
    const int l31 = lane & 31, hi = lane >> 5;
    const int wq = w >> 1, wk = w & 1;
    const int bh = blockIdx.y, qbase = blockIdx.x * 64;
    const __hip_bfloat16* qp = q + ((size_t)bh * Nseq + qbase) * Hd;
    const __hip_bfloat16* kp = k + (size_t)bh * Nseq * Hd;
    const __hip_bfloat16* vp = vt + (size_t)bh * Hd * Nseq;
    const int r8 = tid >> 3, s8 = tid & 7;

    {   // Q: 64 rows x 32, 4-slot xor swizzle
        int r = tid >> 2, sl = tid & 3;
        gload16(qp + r * 32 + ((sl ^ (r & 3)) * 8), Qs + w * 512);
    }
    #pragma unroll
    for (int par = 0; par < 2; par++) {  // pair 0 (chunks 0,1) -> buf 0
        gload16(kp + (par * 64 + 2 * r8 + (s8 >> 2)) * 32 + (((s8 & 3) ^ (r8 & 3)) * 8),
                KsB + par * 2048 + w * 512);
        gload16(vp + (size_t)r8 * Nseq + par * 64 + ((s8 ^ (r8 & 7)) * 8),
                VsB + par * 2048 + w * 512);
    }
    __syncthreads();

    const int qrow = wq * 32 + l31;
    short8 qf0 = *(const short8*)&Qs[qrow * 32 + ((hi ^ (l31 & 3)) * 8)];
    short8 qf1 = *(const short8*)&Qs[qrow * 32 + (((2 + hi) ^ (l31 & 3)) * 8)];

    f32x16 O;
    #pragma unroll
    for (int i = 0; i < 16; i++) O[i] = 0.f;
    float sm = 0.f;

    for (int t = 0; t < 16; t++) {
        const int buf = t & 1;
        if (t + 1 < 16) {
            const int kb2 = (t + 1) * 128;
            #pragma unroll
            for (int par = 0; par < 2; par++) {
                gload16(kp + (kb2 + par * 64 + 2 * r8 + (s8 >> 2)) * 32 + (((s8 & 3) ^ (r8 & 3)) * 8),
                        KsB + ((buf ^ 1) * 2 + par) * 2048 + w * 512);
                gload16(vp + (size_t)r8 * Nseq + kb2 + par * 64 + ((s8 ^ (r8 & 7)) * 8),
                        VsB + ((buf ^ 1) * 2 + par) * 2048 + w * 512);
            }
        }
        const __hip_bfloat16* Kc = KsB + (buf * 2 + wk) * 2048;
        const __hip_bfloat16* Vc = VsB + (buf * 2 + wk) * 2048;
        f32x16 St0, St1;
        #pragma unroll
        for (int i = 0; i < 16; i++) { St0[i] = 0.f; St1[i] = 0.f; }
        {
            int pr = l31 >> 1, elb = pr * 64 + (l31 & 1) * 32;
            short8 kf0 = *(const short8*)&Kc[elb + ((hi ^ (pr & 3)) * 8)];
            short8 kf1 = *(const short8*)&Kc[elb + (((2 + hi) ^ (pr & 3)) * 8)];
            St0 = __builtin_amdgcn_mfma_f32_32x32x16_bf16(kf0, qf0, St0, 0, 0, 0);
            St0 = __builtin_amdgcn_mfma_f32_32x32x16_bf16(kf1, qf1, St0, 0, 0, 0);
        }
        {
            int pr = 16 + (l31 >> 1), elb = pr * 64 + (l31 & 1) * 32;
            short8 kf0 = *(const short8*)&Kc[elb + ((hi ^ (pr & 3)) * 8)];
            short8 kf1 = *(const short8*)&Kc[elb + (((2 + hi) ^ (pr & 3)) * 8)];
            St1 = __builtin_amdgcn_mfma_f32_32x32x16_bf16(kf0, qf0, St1, 0, 0, 0);
            St1 = __builtin_amdgcn_mfma_f32_32x32x16_bf16(kf1, qf1, St1, 0, 0, 0);
        }
        int pk0[8], pk1[8];
        #pragma unroll
        for (int p = 0; p < 8; p++) {
            float a = __builtin_amdgcn_exp2f(St0[2 * p]);
            float b = __builtin_amdgcn_exp2f(St0[2 * p + 1]);
            sm += a + b;
            pk0[p] = pk2bf(a, b);
        }
        #pragma unroll
        for (int p = 0; p < 8; p++) {
            float a = __builtin_amdgcn_exp2f(St1[2 * p]);
            float b = __builtin_amdgcn_exp2f(St1[2 * p + 1]);
            sm += a + b;
            pk1[p] = pk2bf(a, b);
        }
        #pragma unroll
        for (int tt = 0; tt < 4; tt++) {
            const int* PK = (tt >> 1) ? pk1 : pk0;
            const int base = 4 * (tt & 1);
            int keep0 = hi ? PK[base + 2] : PK[base + 0];
            int keep1 = hi ? PK[base + 3] : PK[base + 1];
            int send0 = hi ? PK[base + 0] : PK[base + 2];
            int send1 = hi ? PK[base + 1] : PK[base + 3];
            int x0 = __shfl_xor(send0, 32);
            int x1 = __shfl_xor(send1, 32);
            I4S8 u;
            u.i[0] = hi ? x0 : keep0;
            u.i[1] = hi ? x1 : keep1;
            u.i[2] = hi ? keep0 : x0;
            u.i[3] = hi ? keep1 : x1;
            short8 vf = *(const short8*)&Vc[l31 * 64 + (((2 * tt + hi) ^ (l31 & 7)) * 8)];
            O = __builtin_amdgcn_mfma_f32_32x32x16_bf16(u.s, vf, O, 0, 0, 0);
        }
        __syncthreads();
    }
    sm += __shfl_xor(sm, 32);
    if (wk == 1) {
        #pragma unroll
        for (int j = 0; j < 16; j++) RedO[(wq * 16 + j) * 64 + lane] = O[j];
        if (hi == 0) RedS[wq * 32 + l31] = sm;
    }
    __syncthreads();
    if (wk == 0) {
        #pragma unroll
        for (int j = 0; j < 16; j++) O[j] += RedO[(wq * 16 + j) * 64 + lane];
        sm += RedS[wq * 32 + l31];
        if (hi == 0) smS[wq * 32 + l31] = sm;
    }
    __syncthreads();
    if (wk == 0) {
        const int bb = bh >> 3, hh = bh & 7;
        #pragma unroll
        for (int m = 0; m < 4; m++) {
            float4 sv = *(const float4*)&smS[wq * 32 + 8 * m + 4 * hi];
            #pragma unroll
            for (int i = 0; i < 4; i++) {
                int n = qbase + wq * 32 + 8 * m + 4 * hi + i;
                att[((size_t)(bb * Nseq + n)) * Dm + hh * Hd + l31] =
                    __float2bfloat16(O[4 * m + i] * (1.0f / sv[i]));
            }
        }
    }
}

// ---------------- tail_fused: proj + residual + LN2 + FFN1 + FFN2 ----------
// Grid 256 blocks x 256 thr (1 block/CU, __launch_bounds__(256,1) -> free
// VGPRs). Block owns 32 rows; wave w owns output cols w*64 for proj AND ffn2
// (same cols -> x2 residual lives entirely in registers). LN2 via 1KB LDS
// cross-wave stats. h2 and p round-trip through swizzled LDS (C->A layout).
// All W tiles per-wave gload16-staged, double-buffered.
__global__ __launch_bounds__(256, 1) void tail_fused(
    const __hip_bfloat16* __restrict__ att, const __hip_bfloat16* __restrict__ wpT,
    const float* __restrict__ b_proj, const float* __restrict__ x,
    const float* __restrict__ g2, const float* __restrict__ bv2,
    const __hip_bfloat16* __restrict__ w1T, const float* __restrict__ b1,
    const __hip_bfloat16* __restrict__ w2T, const float* __restrict__ b2,
    float* __restrict__ out) {
    __shared__ __align__(16) __hip_bfloat16 WS[2][4][4096];  // 64 KB, per-buf per-wave
    __shared__ __align__(16) __hip_bfloat16 AH[8192];        // 16 KB: att tile, then h2
    __shared__ __align__(16) __hip_bfloat16 PS[16384];       // 32 KB: relu(ffn1) tile
    __shared__ float red[4][32][2];
    __shared__ float muS[32], rsS[32];

    const int tid = threadIdx.x, w = tid >> 6, lane = tid & 63;
    const int lm = lane & 15, lq = lane >> 4;
    const int R0 = blockIdx.x * 32;
    const int c0 = w * 64;          // proj/ffn2 col base for this wave
    const int c0f = w * 128;        // ffn1 col base

    // ---- stage att tile (32x256, 4 chunk-regions, 8-slot xor swizzle) ----
    {
        const int srow = tid >> 3, ssl = tid & 7;
        #pragma unroll
        for (int kt = 0; kt < 4; kt++)
            gload16(att + (size_t)(R0 + srow) * 256 + kt * 64 + ((ssl ^ (srow & 7)) * 8),
                    AH + kt * 2048 + w * 512);
    }
    // ---- stage wpT kt=0 into buf 0 (per-wave 64x64) ----
    #pragma unroll
    for (int ri = 0; ri < 8; ri++) {
        int r = ri * 8 + (lane >> 3), sl = lane & 7;
        gload16(wpT + (size_t)(c0 + r) * 256 + ((sl ^ (r & 7)) * 8), &WS[0][w][ri * 512]);
    }
    __syncthreads();

    // ---- A-frags -> regs; x residual -> regs ----
    short8 aF[2][4][2];
    #pragma unroll
    for (int mf = 0; mf < 2; mf++) {
        int r = mf * 16 + lm;
        #pragma unroll
        for (int kt = 0; kt < 4; kt++)
            #pragma unroll
            for (int ks = 0; ks < 2; ks++)
                aF[mf][kt][ks] = *(const short8*)&AH[kt * 2048 + r * 64 +
                                                    (((ks * 4 + lq) ^ (lm & 7)) * 8)];
    }
    float xr[2][4][4];
    #pragma unroll
    for (int mf = 0; mf < 2; mf++)
        #pragma unroll
        for (int r = 0; r < 4; r++) {
            int row = R0 + mf * 16 + lq * 4 + r;
            #pragma unroll
            for (int nf = 0; nf < 4; nf++)
                xr[mf][nf][r] = x[(size_t)row * 256 + c0 + nf * 16 + lm];
        }

    // ---- P1: proj GEMM (K=256, BK=64 dbuf) ----
    f32x4 acc[2][4];
    #pragma unroll
    for (int i = 0; i < 2; i++)
        #pragma unroll
        for (int j = 0; j < 4; j++) acc[i][j] = (f32x4){0.f, 0.f, 0.f, 0.f};
    for (int kt = 0; kt < 4; kt++) {
        const int buf = kt & 1;
        if (kt) __syncthreads();
        if (kt + 1 < 4) {
            #pragma unroll
            for (int ri = 0; ri < 8; ri++) {
                int r = ri * 8 + (lane >> 3), sl = lane & 7;
                gload16(wpT + (size_t)(c0 + r) * 256 + (kt + 1) * 64 + ((sl ^ (r & 7)) * 8),
                        &WS[buf ^ 1][w][ri * 512]);
            }
        }
        #pragma unroll
        for (int ks = 0; ks < 2; ks++)
            #pragma unroll
            for (int nf = 0; nf < 4; nf++) {
                int cc = nf * 16 + lm;
                short8 bfr = *(const short8*)&WS[buf][w][cc * 64 + (((ks * 4 + lq) ^ (lm & 7)) * 8)];
                #pragma unroll
                for (int mf = 0; mf < 2; mf++)
                    acc[mf][nf] = __builtin_amdgcn_mfma_f32_16x16x32_bf16(
                        aF[mf][kt][ks], bfr, acc[mf][nf], 0, 0, 0);
            }
    }
    // x2 = proj + bias + x (stays in xr regs)
    #pragma unroll
    for (int nf = 0; nf < 4; nf++) {
        float bp = b_proj[c0 + nf * 16 + lm];
        #pragma unroll
        for (int mf = 0; mf < 2; mf++)
            #pragma unroll
            for (int r = 0; r < 4; r++) xr[mf][nf][r] += acc[mf][nf][r] + bp;
    }

    // ---- LN2 stats: per-wave 64-col partials -> LDS -> 32 finalizers ----
    #pragma unroll
    for (int mf = 0; mf < 2; mf++)
        #pragma unroll
        for (int r = 0; r < 4; r++) {
            float s = 0.f, ss = 0.f;
            #pragma unroll
            for (int nf = 0; nf < 4; nf++) {
                float v = xr[mf][nf][r];
                s += v; ss += v * v;
            }
            #pragma unroll
            for (int off = 1; off <= 8; off <<= 1) {
                s  += __shfl_xor(s, off);
                ss += __shfl_xor(ss, off);
            }
            if (lm == 0) {
                int row = mf * 16 + lq * 4 + r;
                red[w][row][0] = s;
                red[w][row][1] = ss;
            }
        }
    // prefetch ffn1 kt=0 (buf0) while LN finishes (per-wave 128x32)
    #pragma unroll
    for (int ri = 0; ri < 8; ri++) {
        int r = ri * 16 + (lane >> 2), sl = lane & 3;
        gload16(w1T + (size_t)(c0f + r) * 256 + ((sl ^ (r & 3)) * 8), &WS[0][w][ri * 512]);
    }
    __syncthreads();
    if (tid < 32) {
        float s = red[0][tid][0] + red[1][tid][0] + red[2][tid][0] + red[3][tid][0];
        float ss = red[0][tid][1] + red[1][tid][1] + red[2][tid][1] + red[3][tid][1];
        float mu = s * (1.0f / 256.0f);
        muS[tid] = mu;
        rsS[tid] = rsqrtf(ss * (1.0f / 256.0f) - mu * mu + EPS_);
    }
    __syncthreads();
    // h2 = LN2(x2)*g2+b2v -> AH (region w, swizzled A-layout)
    #pragma unroll
    for (int mf = 0; mf < 2; mf++)
        #pragma unroll
        for (int r = 0; r < 4; r++) {
            int row = mf * 16 + lq * 4 + r;
            float mu = muS[row], rs = rsS[row];
            int rw7 = row & 7;
            #pragma unroll
            for (int nf = 0; nf < 4; nf++) {
                int c = c0 + nf * 16 + lm;
                float h = (xr[mf][nf][r] - mu) * rs * g2[c] + bv2[c];
                int slc = nf * 2 + (lm >> 3);
                AH[w * 2048 + row * 64 + ((slc ^ rw7) * 8) + (lm & 7)] = __float2bfloat16(h);
            }
        }
    __syncthreads();

    // ---- F1: ffn1 GEMM (K=256, BK=32 dbuf, wave cols c0f..c0f+128) ----
    f32x4 acc2[2][8];
    #pragma unroll
    for (int i = 0; i < 2; i++)
        #pragma unroll
        for (int j = 0; j < 8; j++) acc2[i][j] = (f32x4){0.f, 0.f, 0.f, 0.f};
    for (int kt = 0; kt < 8; kt++) {
        const int buf = kt & 1;
        if (kt) __syncthreads();
        if (kt + 1 < 8) {
            #pragma unroll
            for (int ri = 0; ri < 8; ri++) {
                int r = ri * 16 + (lane >> 2), sl = lane & 3;
                gload16(w1T + (size_t)(c0f + r) * 256 + (kt + 1) * 32 + ((sl ^ (r & 3)) * 8),
                        &WS[buf ^ 1][w][ri * 512]);
            }
        }
        short8 aA[2];
        #pragma unroll
        for (int mf = 0; mf < 2; mf++) {
            int r = mf * 16 + lm;
            aA[mf] = *(const short8*)&AH[(kt >> 1) * 2048 + r * 64 +
                                         ((((kt & 1) * 4 + lq) ^ (lm & 7)) * 8)];
        }
        #pragma unroll
        for (int nf = 0; nf < 8; nf++) {
            int cc = nf * 16 + lm;
            short8 bfr = *(const short8*)&WS[buf][w][cc * 32 + ((lq ^ (lm & 3)) * 8)];
            #pragma unroll
            for (int mf = 0; mf < 2; mf++)
                acc2[mf][nf] = __builtin_amdgcn_mfma_f32_16x16x32_bf16(
                    aA[mf], bfr, acc2[mf][nf], 0, 0, 0);
        }
    }
    // prefetch ffn2 kt=0 (buf0)
    #pragma unroll
    for (int ri = 0; ri < 8; ri++) {
        int r = ri * 8 + (lane >> 3), sl = lane & 7;
        gload16(w2T + (size_t)(c0 + r) * 512 + ((sl ^ (r & 7)) * 8), &WS[0][w][ri * 512]);
    }
    // p = relu(ffn1 + b1) -> PS (swizzled A-layout over 512 cols)
    #pragma unroll
    for (int nf = 0; nf < 8; nf++) {
        int c = c0f + nf * 16 + lm;
        float bb1 = b1[c];
        int kt8 = w * 2 + (nf >> 2);
        int slc = (nf & 3) * 2 + (lm >> 3);
        #pragma unroll
        for (int mf = 0; mf < 2; mf++)
            #pragma unroll
            for (int r = 0; r < 4; r++) {
                int row = mf * 16 + lq * 4 + r;
                float p = fmaxf(acc2[mf][nf][r] + bb1, 0.f);
                PS[kt8 * 2048 + row * 64 + ((slc ^ (row & 7)) * 8) + (lm & 7)] =
                    __float2bfloat16(p);
            }
    }
    __syncthreads();

    // ---- F2: ffn2 GEMM (K=512, BK=64 dbuf) + b2 + x2(regs) -> out ----
    f32x4 acc3[2][4];
    #pragma unroll
    for (int i = 0; i < 2; i++)
        #pragma unroll
        for (int j = 0; j < 4; j++) acc3[i][j] = (f32x4){0.f, 0.f, 0.f, 0.f};
    for (int kt = 0; kt < 8; kt++) {
        const int buf = kt & 1;
        if (kt) __syncthreads();
        if (kt + 1 < 8) {
            #pragma unroll
            for (int ri = 0; ri < 8; ri++) {
                int r = ri * 8 + (lane >> 3), sl = lane & 7;
                gload16(w2T + (size_t)(c0 + r) * 512 + (kt + 1) * 64 + ((sl ^ (r & 7)) * 8),
                        &WS[buf ^ 1][w][ri * 512]);
            }
        }
        #pragma unroll
        for (int ks = 0; ks < 2; ks++) {
            short8 aP[2];
            #pragma unroll
            for (int mf = 0; mf < 2; mf++) {
                int r = mf * 16 + lm;
                aP[mf] = *(const short8*)&PS[kt * 2048 + r * 64 +
                                             (((ks * 4 + lq) ^ (lm & 7)) * 8)];
            }
            #pragma unroll
            for (int nf = 0; nf < 4; nf++) {
                int cc = nf * 16 + lm;
                short8 bfr = *(const short8*)&WS[buf][w][cc * 64 + (((ks * 4 + lq) ^ (lm & 7)) * 8)];
                #pragma unroll
                for (int mf = 0; mf < 2; mf++)
                    acc3[mf][nf] = __builtin_amdgcn_mfma_f32_16x16x32_bf16(
                        aP[mf], bfr, acc3[mf][nf], 0, 0, 0);
            }
        }
    }
    #pragma unroll
    for (int nf = 0; nf < 4; nf++) {
        int c = c0 + nf * 16 + lm;
        float bb2 = b2[c];
        #pragma unroll
        for (int mf = 0; mf < 2; mf++)
            #pragma unroll
            for (int r = 0; r < 4; r++) {
                int row = R0 + mf * 16 + lq * 4 + r;
                out[(size_t)row * 256 + c] = acc3[mf][nf][r] + bb2 + xr[mf][nf][r];
            }
    }
}

extern "C" void kernel_launch(void* const* d_in, const int* in_sizes, int n_in,
                              void* d_out, int out_size, void* d_ws, size_t ws_size,
                              hipStream_t stream) {
    const float* x      = (const float*)d_in[0];
    const float* fcos   = (const float*)d_in[1];
    const float* fsin   = (const float*)d_in[2];
    const float* w_qkv  = (const float*)d_in[3];
    const float* b_qkv  = (const float*)d_in[4];
    const float* w_proj = (const float*)d_in[5];
    const float* b_proj = (const float*)d_in[6];
    const float* ln1_g  = (const float*)d_in[7];
    const float* ln1_b  = (const float*)d_in[8];
    const float* ln2_g  = (const float*)d_in[9];
    const float* ln2_b  = (const float*)d_in[10];
    const float* w1     = (const float*)d_in[11];
    const float* b1     = (const float*)d_in[12];
    const float* w2     = (const float*)d_in[13];
    const float* b2     = (const float*)d_in[14];
    float* out = (float*)d_out;
    char* base = (char*)d_ws;
    const size_t MB = (size_t)1 << 20;

    __hip_bfloat16* h   = (__hip_bfloat16*)(base);            // 4 MB
    __hip_bfloat16* qb  = (__hip_bfloat16*)(base + 4 * MB);
    __hip_bfloat16* kbf = (__hip_bfloat16*)(base + 8 * MB);
    __hip_bfloat16* vtb = (__hip_bfloat16*)(base + 12 * MB);  // transposed [B,H,d,N]
    __hip_bfloat16* att = (__hip_bfloat16*)(base + 16 * MB);
    __hip_bfloat16* wqT = (__hip_bfloat16*)(base + 20 * MB);            // 768x256
    __hip_bfloat16* wpT = (__hip_bfloat16*)(base + 20 * MB + 393216);   // 256x256
    __hip_bfloat16* w1T = (__hip_bfloat16*)(base + 20 * MB + 524288);   // 512x256
    __hip_bfloat16* w2T = (__hip_bfloat16*)(base + 20 * MB + 786432);   // 256x512

    prep_kernel<<<2560, 256, 0, stream>>>(x, ln1_g, ln1_b, h,
                                          w_qkv, w_proj, w1, w2, wqT, wpT, w1T, w2T);
    qkv_mfma<<<dim3(12, 128), 256, 0, stream>>>(h, wqT, b_qkv, fcos, fsin, qb, kbf, vtb);
    attn_mfma<<<dim3(Nseq / 64, Bsz * Hh), 256, 0, stream>>>(qb, kbf, vtb, att);
    tail_fused<<<256, 256, 0, stream>>>(att, wpT, b_proj, x, ln2_g, ln2_b,
                                        w1T, b1, w2T, b2, out);
}

// Round 9
// 169.412 us; speedup vs baseline: 1.3595x; 1.0183x over previous
//
#include <hip/hip_runtime.h>
#include <hip/hip_bf16.h>
#include <math.h>

#define Bsz 4
#define Nseq 2048
#define Dm 256
#define Hh 8
#define Hd 32
#define EPS_ 1e-5f
#define SCALE_ 0.17677669529663687f               // 1/sqrt(32)
#define QSC_ (0.17677669529663687f * 1.4426950408889634f)  // fold log2(e) for exp2

typedef __attribute__((ext_vector_type(8))) short short8;
typedef __attribute__((ext_vector_type(4))) short short4v;
typedef __attribute__((ext_vector_type(4))) float f32x4;
typedef __attribute__((ext_vector_type(16))) float f32x16;

// async global->LDS, 16B per lane. LDS dest = wave-uniform base + lane*16.
__device__ __forceinline__ void gload16(const void* g, void* l) {
    __builtin_amdgcn_global_load_lds(
        (const __attribute__((address_space(1))) void*)g,
        (__attribute__((address_space(3))) void*)l, 16, 0, 0);
}

__device__ __forceinline__ short bf16s(float f) {
    __hip_bfloat16 h = __float2bfloat16(f);
    return *(short*)&h;
}

union FU { float f; unsigned u; };

// pack two fp32 -> (bf16(a) | bf16(b)<<16) via single v_perm_b32 (truncation)
__device__ __forceinline__ int pk2bf(float a, float b) {
    FU ua, ub; ua.f = a; ub.f = b;
    return (int)__builtin_amdgcn_perm(ub.u, ua.u, 0x07060302u);
}

union I4S8 { int i[4]; short8 s; };

// ---------------- prep: LN1 (bid<2048) + weight transpose (bid>=2048) ------
__global__ __launch_bounds__(256) void prep_kernel(
    const float* __restrict__ x, const float* __restrict__ g1,
    const float* __restrict__ b1v, __hip_bfloat16* __restrict__ hout,
    const float* __restrict__ s0, const float* __restrict__ s1,
    const float* __restrict__ s2, const float* __restrict__ s3,
    __hip_bfloat16* __restrict__ d0, __hip_bfloat16* __restrict__ d1,
    __hip_bfloat16* __restrict__ d2, __hip_bfloat16* __restrict__ d3) {
    __shared__ float t[32][33];
    if (blockIdx.x < 2048) {
        int row  = blockIdx.x * 4 + (threadIdx.x >> 6);
        int lane = threadIdx.x & 63;
        const float* xr = x + (size_t)row * Dm;
        float4 v = *(const float4*)(xr + lane * 4);
        float s  = v.x + v.y + v.z + v.w;
        float ss = v.x * v.x + v.y * v.y + v.z * v.z + v.w * v.w;
        #pragma unroll
        for (int off = 32; off; off >>= 1) {
            s  += __shfl_xor(s, off);
            ss += __shfl_xor(ss, off);
        }
        float mu  = s * (1.0f / Dm);
        float var = ss * (1.0f / Dm) - mu * mu;
        float rs  = rsqrtf(var + EPS_);
        float4 gv = *(const float4*)(g1 + lane * 4);
        float4 bv = *(const float4*)(b1v + lane * 4);
        short4v o4 = { bf16s((v.x - mu) * rs * gv.x + bv.x),
                       bf16s((v.y - mu) * rs * gv.y + bv.y),
                       bf16s((v.z - mu) * rs * gv.z + bv.z),
                       bf16s((v.w - mu) * rs * gv.w + bv.w) };
        *(short4v*)(hout + (size_t)row * Dm + lane * 4) = o4;
        return;
    }
    int bid = blockIdx.x - 2048;
    const float* src; __hip_bfloat16* dst; int K, N, tb;
    if (bid < 192)      { src = s0; dst = d0; K = 256; N = 768; tb = bid; }
    else if (bid < 256) { src = s1; dst = d1; K = 256; N = 256; tb = bid - 192; }
    else if (bid < 384) { src = s2; dst = d2; K = 256; N = 512; tb = bid - 256; }
    else                { src = s3; dst = d3; K = 512; N = 256; tb = bid - 384; }
    int tn = N >> 5;
    int k0 = (tb / tn) * 32, n0 = (tb % tn) * 32;
    int c = threadIdx.x & 31, r0 = threadIdx.x >> 5;
    #pragma unroll
    for (int i = 0; i < 4; i++) {
        int r = r0 + i * 8;
        t[r][c] = src[(size_t)(k0 + r) * N + n0 + c];
    }
    __syncthreads();
    #pragma unroll
    for (int i = 0; i < 4; i++) {
        int n = r0 + i * 8;
        dst[(size_t)(n0 + n) * K + k0 + c] = __float2bfloat16(t[c][n]);
    }
}

// ---------------- QKV: BK=64 dbuf MFMA GEMM + bias/RoPE/scatter ------------
__global__ __launch_bounds__(256) void qkv_mfma(const __hip_bfloat16* __restrict__ A,
                                                const __hip_bfloat16* __restrict__ Wt,
                                                const float* __restrict__ bias,
                                                const float* __restrict__ fcos,
                                                const float* __restrict__ fsin,
                                                __hip_bfloat16* __restrict__ qout,
                                                __hip_bfloat16* __restrict__ kout,
                                                __hip_bfloat16* __restrict__ vt) {
    const int K = 256;
    __shared__ __align__(16) __hip_bfloat16 As[2][64 * 64];
    __shared__ __align__(16) __hip_bfloat16 Bs[2][64 * 64];
    const int tid = threadIdx.x, w = tid >> 6, lane = tid & 63;
    const int lm = lane & 15, lq = lane >> 4;
    const int bm = blockIdx.y * 64, bn = blockIdx.x * 64;
    f32x4 acc[4];
    #pragma unroll
    for (int j = 0; j < 4; j++) acc[j] = (f32x4){0.f, 0.f, 0.f, 0.f};

    const int sr = tid >> 3, ssl = tid & 7;
    const int sgk = (ssl ^ (sr & 7)) * 8;
    const int sr2 = 32 + sr;
    const int sgk2 = (ssl ^ (sr2 & 7)) * 8;

    gload16(A + (size_t)(bm + sr) * K + sgk, &As[0][w * 512]);
    gload16(A + (size_t)(bm + sr2) * K + sgk2, &As[0][2048 + w * 512]);
    gload16(Wt + (size_t)(bn + sr) * K + sgk, &Bs[0][w * 512]);
    gload16(Wt + (size_t)(bn + sr2) * K + sgk2, &Bs[0][2048 + w * 512]);

    const int arow = w * 16 + lm;
    const int ar7 = arow & 7;
    for (int t = 0; t < K / 64; t++) {
        const int buf = t & 1;
        __syncthreads();
        if (t + 1 < K / 64) {
            int k0 = (t + 1) * 64;
            gload16(A + (size_t)(bm + sr) * K + k0 + sgk, &As[buf ^ 1][w * 512]);
            gload16(A + (size_t)(bm + sr2) * K + k0 + sgk2, &As[buf ^ 1][2048 + w * 512]);
            gload16(Wt + (size_t)(bn + sr) * K + k0 + sgk, &Bs[buf ^ 1][w * 512]);
            gload16(Wt + (size_t)(bn + sr2) * K + k0 + sgk2, &Bs[buf ^ 1][2048 + w * 512]);
        }
        #pragma unroll
        for (int ks = 0; ks < 2; ks++) {
            short8 a = *(const short8*)&As[buf][arow * 64 + (((ks * 4 + lq) ^ ar7) * 8)];
            #pragma unroll
            for (int nf = 0; nf < 4; nf++) {
                int cc = nf * 16 + lm;
                short8 bfr = *(const short8*)&Bs[buf][cc * 64 + (((ks * 4 + lq) ^ (cc & 7)) * 8)];
                acc[nf] = __builtin_amdgcn_mfma_f32_16x16x32_bf16(a, bfr, acc[nf], 0, 0, 0);
            }
        }
    }
    const int seg = bn >> 8;  // 0=q 1=k 2=v, uniform per block
    #pragma unroll
    for (int nf = 0; nf < 4; nf++) {
        int cg = bn + nf * 16 + lm;
        int hh = (cg & 255) >> 5;
        int dd = (nf & 1) * 16 + lm;
        int i0 = dd >> 1;
        float bi = bias[cg];
        #pragma unroll
        for (int r = 0; r < 4; r++) {
            int rg = bm + w * 16 + lq * 4 + r;
            int bb = rg >> 11, n = rg & (Nseq - 1);
            float v = acc[nf][r] + bi;
            if (seg == 2) {
                vt[(((size_t)(bb * Hh + hh)) * Hd + dd) * Nseq + n] = __float2bfloat16(v);
            } else {
                float vp = __shfl_xor(v, 1);
                float cs = fcos[n * 16 + i0], sn = fsin[n * 16 + i0];
                float outv = (dd & 1) ? (vp * sn + v * cs) : (v * cs - vp * sn);
                if (seg == 0) outv *= QSC_;
                __hip_bfloat16* dst = (seg == 0) ? qout : kout;
                dst[(((size_t)(bb * Hh + hh)) * Nseq + n) * Hd + dd] = __float2bfloat16(outv);
            }
        }
    }
}

// ---------------- Flash attention: barrier-free wave-private K-loop --------
// Block = 64 q rows, 4 waves = 2 q-groups x 2 key-halves. Each wave is
// self-sufficient: K chunks -> REGISTERS (A-frag mapping K[key=l31][d=hi*8+j]
// = two 16B loads per 32-key half), V -> wave-private LDS dbuf via gload16.
// No __syncthreads() in the K-loop. Sync discipline: compiler auto-waits on
// K regs; "s_waitcnt vmcnt(8)" before PV ds_reads guarantees (FIFO retire)
// the current V chunk landed; "s_waitcnt lgkmcnt(0)" before the prefetch
// guarantees prior ds_reads consumed before the buffer is overwritten.
__global__ __launch_bounds__(256) void attn_mfma(const __hip_bfloat16* __restrict__ q,
                                                 const __hip_bfloat16* __restrict__ k,
                                                 const __hip_bfloat16* __restrict__ vt,
                                                 __hip_bfloat16* __restrict__ att) {
    __shared__ __align__(16) char smem[4096 + 32768 + 512];
    __hip_bfloat16* Qs = (__hip_bfloat16*)smem;            // 64x32
    __hip_bfloat16* Vw = (__hip_bfloat16*)(smem + 4096);   // [wave][buf][32*64]
    float* RedO = (float*)(smem + 4096);                   // alias V after barrier
    float* RedS = (float*)(smem + 4096 + 8192);
    float* smS  = (float*)(smem + 4096 + 8192 + 256);

    const int tid = threadIdx.x, w = tid >> 6, lane = tid & 63;
    const int l31 = lane & 31, hi = lane >> 5;
    const int wq = w >> 1, wk = w & 1;
    const int bh = blockIdx.y, qbase = blockIdx.x * 64;
    const __hip_bfloat16* qp = q + ((size_t)bh * Nseq + qbase) * Hd;
    const __hip_bfloat16* kp = k + (size_t)bh * Nseq * Hd;
    const __hip_bfloat16* vp = vt + (size_t)bh * Hd * Nseq;

    {   // Q cooperative stage (4-slot xor swizzle)
        int r = tid >> 2, sl = tid & 3;
        gload16(qp + r * 32 + ((sl ^ (r & 3)) * 8), Qs + w * 512);
    }
    // wave-private V double buffer; stage chunk c0 = wk into buf 0
    __hip_bfloat16* myV = Vw + w * 4096;      // 4096 elems = 8KB per wave
    const int vd = (lane >> 3) & 7, vs = lane & 7;
    const int szv = (vs ^ vd) * 8;
    #pragma unroll
    for (int i = 0; i < 4; i++)
        gload16(vp + (size_t)(i * 8 + vd) * Nseq + wk * 64 + szv, myV + i * 512);
    // K chunk wk -> registers (issued after V: FIFO retire covers V)
    const __hip_bfloat16* kb = kp + (size_t)wk * 64 * Hd + l31 * Hd + hi * 8;
    short8 kf0 = *(const short8*)(kb);
    short8 kf1 = *(const short8*)(kb + 16);
    short8 kf2 = *(const short8*)(kb + 1024);
    short8 kf3 = *(const short8*)(kb + 1040);
    __syncthreads();   // Q visible (drains all vmcnt -> clean start)

    const int qrow = wq * 32 + l31;
    short8 qf0 = *(const short8*)&Qs[qrow * 32 + ((hi ^ (l31 & 3)) * 8)];
    short8 qf1 = *(const short8*)&Qs[qrow * 32 + (((2 + hi) ^ (l31 & 3)) * 8)];

    f32x16 O;
    #pragma unroll
    for (int i = 0; i < 16; i++) O[i] = 0.f;
    float sm = 0.f;

    for (int t = 0; t < 16; t++) {
        const int cur = t & 1;
        short8 nk0, nk1, nk2, nk3;
        if (t + 1 < 16) {
            const int c = 2 * (t + 1) + wk;
            // prior ds_reads consumed before overwriting buf cur^1
            asm volatile("s_waitcnt lgkmcnt(0)" ::: "memory");
            #pragma unroll
            for (int i = 0; i < 4; i++)
                gload16(vp + (size_t)(i * 8 + vd) * Nseq + c * 64 + szv,
                        myV + (cur ^ 1) * 2048 + i * 512);
            const __hip_bfloat16* kbn = kp + (size_t)c * 64 * Hd + l31 * Hd + hi * 8;
            nk0 = *(const short8*)(kbn);
            nk1 = *(const short8*)(kbn + 16);
            nk2 = *(const short8*)(kbn + 1024);
            nk3 = *(const short8*)(kbn + 1040);
        }
        // S^T = K·Q^T (keys 0-31 in St0, 32-63 in St1); K frags in regs
        f32x16 St0, St1;
        #pragma unroll
        for (int i = 0; i < 16; i++) { St0[i] = 0.f; St1[i] = 0.f; }
        St0 = __builtin_amdgcn_mfma_f32_32x32x16_bf16(kf0, qf0, St0, 0, 0, 0);
        St0 = __builtin_amdgcn_mfma_f32_32x32x16_bf16(kf1, qf1, St0, 0, 0, 0);
        St1 = __builtin_amdgcn_mfma_f32_32x32x16_bf16(kf2, qf0, St1, 0, 0, 0);
        St1 = __builtin_amdgcn_mfma_f32_32x32x16_bf16(kf3, qf1, St1, 0, 0, 0);
        // exp2 + single-instruction pair pack
        int pk0[8], pk1[8];
        #pragma unroll
        for (int p = 0; p < 8; p++) {
            float a = __builtin_amdgcn_exp2f(St0[2 * p]);
            float b = __builtin_amdgcn_exp2f(St0[2 * p + 1]);
            sm += a + b;
            pk0[p] = pk2bf(a, b);
        }
        #pragma unroll
        for (int p = 0; p < 8; p++) {
            float a = __builtin_amdgcn_exp2f(St1[2 * p]);
            float b = __builtin_amdgcn_exp2f(St1[2 * p + 1]);
            sm += a + b;
            pk1[p] = pk2bf(a, b);
        }
        // current V chunk guaranteed resident: <=8 outstanding = next chunk's
        asm volatile("s_waitcnt vmcnt(8)" ::: "memory");
        #pragma unroll
        for (int tt = 0; tt < 4; tt++) {
            const int* PK = (tt >> 1) ? pk1 : pk0;
            const int base = 4 * (tt & 1);
            int keep0 = hi ? PK[base + 2] : PK[base + 0];
            int keep1 = hi ? PK[base + 3] : PK[base + 1];
            int send0 = hi ? PK[base + 0] : PK[base + 2];
            int send1 = hi ? PK[base + 1] : PK[base + 3];
            int x0 = __shfl_xor(send0, 32);
            int x1 = __shfl_xor(send1, 32);
            I4S8 u;
            u.i[0] = hi ? x0 : keep0;
            u.i[1] = hi ? x1 : keep1;
            u.i[2] = hi ? keep0 : x0;
            u.i[3] = hi ? keep1 : x1;
            short8 vf = *(const short8*)&myV[cur * 2048 + l31 * 64 +
                                            (((2 * tt + hi) ^ (l31 & 7)) * 8)];
            O = __builtin_amdgcn_mfma_f32_32x32x16_bf16(u.s, vf, O, 0, 0, 0);
        }
        if (t + 1 < 16) { kf0 = nk0; kf1 = nk1; kf2 = nk2; kf3 = nk3; }
    }
    sm += __shfl_xor(sm, 32);
    __syncthreads();   // all waves out of the loop; V regions dead
    if (wk == 1) {
        #pragma unroll
        for (int j = 0; j < 16; j++) RedO[(wq * 16 + j) * 64 + lane] = O[j];
        if (hi == 0) RedS[wq * 32 + l31] = sm;
    }
    __syncthreads();
    if (wk == 0) {
        #pragma unroll
        for (int j = 0; j < 16; j++) O[j] += RedO[(wq * 16 + j) * 64 + lane];
        sm += RedS[wq * 32 + l31];
        if (hi == 0) smS[wq * 32 + l31] = sm;
    }
    __syncthreads();
    if (wk == 0) {
        const int bb = bh >> 3, hh = bh & 7;
        #pragma unroll
        for (int m = 0; m < 4; m++) {
            float4 sv = *(const float4*)&smS[wq * 32 + 8 * m + 4 * hi];
            #pragma unroll
            for (int i = 0; i < 4; i++) {
                int n = qbase + wq * 32 + 8 * m + 4 * hi + i;
                att[((size_t)(bb * Nseq + n)) * Dm + hh * Hd + l31] =
                    __float2bfloat16(O[4 * m + i] * (1.0f / sv[i]));
            }
        }
    }
}

// ---------------- tail_fused: proj + residual + LN2 + FFN1 + FFN2 ----------
__global__ __launch_bounds__(256, 1) void tail_fused(
    const __hip_bfloat16* __restrict__ att, const __hip_bfloat16* __restrict__ wpT,
    const float* __restrict__ b_proj, const float* __restrict__ x,
    const float* __restrict__ g2, const float* __restrict__ bv2,
    const __hip_bfloat16* __restrict__ w1T, const float* __restrict__ b1,
    const __hip_bfloat16* __restrict__ w2T, const float* __restrict__ b2,
    float* __restrict__ out) {
    __shared__ __align__(16) __hip_bfloat16 WS[2][4][4096];  // 64 KB
    __shared__ __align__(16) __hip_bfloat16 AH[8192];        // att tile, then h2
    __shared__ __align__(16) __hip_bfloat16 PS[16384];       // relu(ffn1) tile
    __shared__ float red[4][32][2];
    __shared__ float muS[32], rsS[32];

    const int tid = threadIdx.x, w = tid >> 6, lane = tid & 63;
    const int lm = lane & 15, lq = lane >> 4;
    const int R0 = blockIdx.x * 32;
    const int c0 = w * 64;
    const int c0f = w * 128;

    {
        const int srow = tid >> 3, ssl = tid & 7;
        #pragma unroll
        for (int kt = 0; kt < 4; kt++)
            gload16(att + (size_t)(R0 + srow) * 256 + kt * 64 + ((ssl ^ (srow & 7)) * 8),
                    AH + kt * 2048 + w * 512);
    }
    #pragma unroll
    for (int ri = 0; ri < 8; ri++) {
        int r = ri * 8 + (lane >> 3), sl = lane & 7;
        gload16(wpT + (size_t)(c0 + r) * 256 + ((sl ^ (r & 7)) * 8), &WS[0][w][ri * 512]);
    }
    __syncthreads();

    short8 aF[2][4][2];
    #pragma unroll
    for (int mf = 0; mf < 2; mf++) {
        int r = mf * 16 + lm;
        #pragma unroll
        for (int kt = 0; kt < 4; kt++)
            #pragma unroll
            for (int ks = 0; ks < 2; ks++)
                aF[mf][kt][ks] = *(const short8*)&AH[kt * 2048 + r * 64 +
                                                    (((ks * 4 + lq) ^ (lm & 7)) * 8)];
    }
    float xr[2][4][4];
    #pragma unroll
    for (int mf = 0; mf < 2; mf++)
        #pragma unroll
        for (int r = 0; r < 4; r++) {
            int row = R0 + mf * 16 + lq * 4 + r;
            #pragma unroll
            for (int nf = 0; nf < 4; nf++)
                xr[mf][nf][r] = x[(size_t)row * 256 + c0 + nf * 16 + lm];
        }

    f32x4 acc[2][4];
    #pragma unroll
    for (int i = 0; i < 2; i++)
        #pragma unroll
        for (int j = 0; j < 4; j++) acc[i][j] = (f32x4){0.f, 0.f, 0.f, 0.f};
    for (int kt = 0; kt < 4; kt++) {
        const int buf = kt & 1;
        if (kt) __syncthreads();
        if (kt + 1 < 4) {
            #pragma unroll
            for (int ri = 0; ri < 8; ri++) {
                int r = ri * 8 + (lane >> 3), sl = lane & 7;
                gload16(wpT + (size_t)(c0 + r) * 256 + (kt + 1) * 64 + ((sl ^ (r & 7)) * 8),
                        &WS[buf ^ 1][w][ri * 512]);
            }
        }
        #pragma unroll
        for (int ks = 0; ks < 2; ks++)
            #pragma unroll
            for (int nf = 0; nf < 4; nf++) {
                int cc = nf * 16 + lm;
                short8 bfr = *(const short8*)&WS[buf][w][cc * 64 + (((ks * 4 + lq) ^ (lm & 7)) * 8)];
                #pragma unroll
                for (int mf = 0; mf < 2; mf++)
                    acc[mf][nf] = __builtin_amdgcn_mfma_f32_16x16x32_bf16(
                        aF[mf][kt][ks], bfr, acc[mf][nf], 0, 0, 0);
            }
    }
    #pragma unroll
    for (int nf = 0; nf < 4; nf++) {
        float bp = b_proj[c0 + nf * 16 + lm];
        #pragma unroll
        for (int mf = 0; mf < 2; mf++)
            #pragma unroll
            for (int r = 0; r < 4; r++) xr[mf][nf][r] += acc[mf][nf][r] + bp;
    }

    #pragma unroll
    for (int mf = 0; mf < 2; mf++)
        #pragma unroll
        for (int r = 0; r < 4; r++) {
            float s = 0.f, ss = 0.f;
            #pragma unroll
            for (int nf = 0; nf < 4; nf++) {
                float v = xr[mf][nf][r];
                s += v; ss += v * v;
            }
            #pragma unroll
            for (int off = 1; off <= 8; off <<= 1) {
                s  += __shfl_xor(s, off);
                ss += __shfl_xor(ss, off);
            }
            if (lm == 0) {
                int row = mf * 16 + lq * 4 + r;
                red[w][row][0] = s;
                red[w][row][1] = ss;
            }
        }
    #pragma unroll
    for (int ri = 0; ri < 8; ri++) {
        int r = ri * 16 + (lane >> 2), sl = lane & 3;
        gload16(w1T + (size_t)(c0f + r) * 256 + ((sl ^ (r & 3)) * 8), &WS[0][w][ri * 512]);
    }
    __syncthreads();
    if (tid < 32) {
        float s = red[0][tid][0] + red[1][tid][0] + red[2][tid][0] + red[3][tid][0];
        float ss = red[0][tid][1] + red[1][tid][1] + red[2][tid][1] + red[3][tid][1];
        float mu = s * (1.0f / 256.0f);
        muS[tid] = mu;
        rsS[tid] = rsqrtf(ss * (1.0f / 256.0f) - mu * mu + EPS_);
    }
    __syncthreads();
    #pragma unroll
    for (int mf = 0; mf < 2; mf++)
        #pragma unroll
        for (int r = 0; r < 4; r++) {
            int row = mf * 16 + lq * 4 + r;
            float mu = muS[row], rs = rsS[row];
            int rw7 = row & 7;
            #pragma unroll
            for (int nf = 0; nf < 4; nf++) {
                int c = c0 + nf * 16 + lm;
                float h = (xr[mf][nf][r] - mu) * rs * g2[c] + bv2[c];
                int slc = nf * 2 + (lm >> 3);
                AH[w * 2048 + row * 64 + ((slc ^ rw7) * 8) + (lm & 7)] = __float2bfloat16(h);
            }
        }
    __syncthreads();

    f32x4 acc2[2][8];
    #pragma unroll
    for (int i = 0; i < 2; i++)
        #pragma unroll
        for (int j = 0; j < 8; j++) acc2[i][j] = (f32x4){0.f, 0.f, 0.f, 0.f};
    for (int kt = 0; kt < 8; kt++) {
        const int buf = kt & 1;
        if (kt) __syncthreads();
        if (kt + 1 < 8) {
            #pragma unroll
            for (int ri = 0; ri < 8; ri++) {
                int r = ri * 16 + (lane >> 2), sl = lane & 3;
                gload16(w1T + (size_t)(c0f + r) * 256 + (kt + 1) * 32 + ((sl ^ (r & 3)) * 8),
                        &WS[buf ^ 1][w][ri * 512]);
            }
        }
        short8 aA[2];
        #pragma unroll
        for (int mf = 0; mf < 2; mf++) {
            int r = mf * 16 + lm;
            aA[mf] = *(const short8*)&AH[(kt >> 1) * 2048 + r * 64 +
                                         ((((kt & 1) * 4 + lq) ^ (lm & 7)) * 8)];
        }
        #pragma unroll
        for (int nf = 0; nf < 8; nf++) {
            int cc = nf * 16 + lm;
            short8 bfr = *(const short8*)&WS[buf][w][cc * 32 + ((lq ^ (lm & 3)) * 8)];
            #pragma unroll
            for (int mf = 0; mf < 2; mf++)
                acc2[mf][nf] = __builtin_amdgcn_mfma_f32_16x16x32_bf16(
                    aA[mf], bfr, acc2[mf][nf], 0, 0, 0);
        }
    }
    #pragma unroll
    for (int ri = 0; ri < 8; ri++) {
        int r = ri * 8 + (lane >> 3), sl = lane & 7;
        gload16(w2T + (size_t)(c0 + r) * 512 + ((sl ^ (r & 7)) * 8), &WS[0][w][ri * 512]);
    }
    #pragma unroll
    for (int nf = 0; nf < 8; nf++) {
        int c = c0f + nf * 16 + lm;
        float bb1 = b1[c];
        int kt8 = w * 2 + (nf >> 2);
        int slc = (nf & 3) * 2 + (lm >> 3);
        #pragma unroll
        for (int mf = 0; mf < 2; mf++)
            #pragma unroll
            for (int r = 0; r < 4; r++) {
                int row = mf * 16 + lq * 4 + r;
                float p = fmaxf(acc2[mf][nf][r] + bb1, 0.f);
                PS[kt8 * 2048 + row * 64 + ((slc ^ (row & 7)) * 8) + (lm & 7)] =
                    __float2bfloat16(p);
            }
    }
    __syncthreads();

    f32x4 acc3[2][4];
    #pragma unroll
    for (int i = 0; i < 2; i++)
        #pragma unroll
        for (int j = 0; j < 4; j++) acc3[i][j] = (f32x4){0.f, 0.f, 0.f, 0.f};
    for (int kt = 0; kt < 8; kt++) {
        const int buf = kt & 1;
        if (kt) __syncthreads();
        if (kt + 1 < 8) {
            #pragma unroll
            for (int ri = 0; ri < 8; ri++) {
                int r = ri * 8 + (lane >> 3), sl = lane & 7;
                gload16(w2T + (size_t)(c0 + r) * 512 + (kt + 1) * 64 + ((sl ^ (r & 7)) * 8),
                        &WS[buf ^ 1][w][ri * 512]);
            }
        }
        #pragma unroll
        for (int ks = 0; ks < 2; ks++) {
            short8 aP[2];
            #pragma unroll
            for (int mf = 0; mf < 2; mf++) {
                int r = mf * 16 + lm;
                aP[mf] = *(const short8*)&PS[kt * 2048 + r * 64 +
                                             (((ks * 4 + lq) ^ (lm & 7)) * 8)];
            }
            #pragma unroll
            for (int nf = 0; nf < 4; nf++) {
                int cc = nf * 16 + lm;
                short8 bfr = *(const short8*)&WS[buf][w][cc * 64 + (((ks * 4 + lq) ^ (lm & 7)) * 8)];
                #pragma unroll
                for (int mf = 0; mf < 2; mf++)
                    acc3[mf][nf] = __builtin_amdgcn_mfma_f32_16x16x32_bf16(
                        aP[mf], bfr, acc3[mf][nf], 0, 0, 0);
            }
        }
    }
    #pragma unroll
    for (int nf = 0; nf < 4; nf++) {
        int c = c0 + nf * 16 + lm;
        float bb2 = b2[c];
        #pragma unroll
        for (int mf = 0; mf < 2; mf++)
            #pragma unroll
            for (int r = 0; r < 4; r++) {
                int row = R0 + mf * 16 + lq * 4 + r;
                out[(size_t)row * 256 + c] = acc3[mf][nf][r] + bb2 + xr[mf][nf][r];
            }
    }
}

extern "C" void kernel_launch(void* const* d_in, const int* in_sizes, int n_in,
                              void* d_out, int out_size, void* d_ws, size_t ws_size,
                              hipStream_t stream) {
    const float* x      = (const float*)d_in[0];
    const float* fcos   = (const float*)d_in[1];
    const float* fsin   = (const float*)d_in[2];
    const float* w_qkv  = (const float*)d_in[3];
    const float* b_qkv  = (const float*)d_in[4];
    const float* w_proj = (const float*)d_in[5];
    const float* b_proj = (const float*)d_in[6];
    const float* ln1_g  = (const float*)d_in[7];
    const float* ln1_b  = (const float*)d_in[8];
    const float* ln2_g  = (const float*)d_in[9];
    const float* ln2_b  = (const float*)d_in[10];
    const float* w1     = (const float*)d_in[11];
    const float* b1     = (const float*)d_in[12];
    const float* w2     = (const float*)d_in[13];
    const float* b2     = (const float*)d_in[14];
    float* out = (float*)d_out;
    char* base = (char*)d_ws;
    const size_t MB = (size_t)1 << 20;

    __hip_bfloat16* h   = (__hip_bfloat16*)(base);            // 4 MB
    __hip_bfloat16* qb  = (__hip_bfloat16*)(base + 4 * MB);
    __hip_bfloat16* kbf = (__hip_bfloat16*)(base + 8 * MB);
    __hip_bfloat16* vtb = (__hip_bfloat16*)(base + 12 * MB);  // transposed [B,H,d,N]
    __hip_bfloat16* att = (__hip_bfloat16*)(base + 16 * MB);
    __hip_bfloat16* wqT = (__hip_bfloat16*)(base + 20 * MB);            // 768x256
    __hip_bfloat16* wpT = (__hip_bfloat16*)(base + 20 * MB + 393216);   // 256x256
    __hip_bfloat16* w1T = (__hip_bfloat16*)(base + 20 * MB + 524288);   // 512x256
    __hip_bfloat16* w2T = (__hip_bfloat16*)(base + 20 * MB + 786432);   // 256x512

    prep_kernel<<<2560, 256, 0, stream>>>(x, ln1_g, ln1_b, h,
                                          w_qkv, w_proj, w1, w2, wqT, wpT, w1T, w2T);
    qkv_mfma<<<dim3(12, 128), 256, 0, stream>>>(h, wqT, b_qkv, fcos, fsin, qb, kbf, vtb);
    attn_mfma<<<dim3(Nseq / 64, Bsz * Hh), 256, 0, stream>>>(qb, kbf, vtb, att);
    tail_fused<<<256, 256, 0, stream>>>(att, wpT, b_proj, x, ln2_g, ln2_b,
                                        w1T, b1, w2T, b2, out);
}